// Round 1
// baseline (5762.328 us; speedup 1.0000x reference)
//
#include <hip/hip_runtime.h>

// RGCN: 2-layer, R=4 relations, N=100000, E=500000/rel, 128->128->64.
// Strategy: GEMM-first (y_r = (x*norm_src)@W_r per node), then edge scatter
// with dst-norm applied at scatter time via f32 global atomics.

constexpr int Nn  = 100000;
constexpr int Rr  = 4;
constexpr int Ee  = 500000;

__global__ __launch_bounds__(256)
void count_deg_kernel(const int* __restrict__ src, const int* __restrict__ dst,
                      unsigned* __restrict__ dsrc, unsigned* __restrict__ ddst)
{
    int gid = blockIdx.x * 256 + threadIdx.x;
    if (gid >= Rr * Ee) return;
    int r = gid / Ee;
    int base = r * Nn;
    atomicAdd(&dsrc[base + src[gid]], 1u);
    atomicAdd(&ddst[base + dst[gid]], 1u);
}

__global__ __launch_bounds__(256)
void make_norms_kernel(const unsigned* __restrict__ deg, float* __restrict__ nrm)
{
    int gid = blockIdx.x * 256 + threadIdx.x;
    if (gid >= 2 * Rr * Nn) return;
    unsigned d = deg[gid];
    nrm[gid] = rsqrtf((float)(d > 0u ? d : 1u));
}

// H[n][j] = sum_r b[r][j]  (bias pre-accumulated; also initializes the buffer)
template<int F>
__global__ __launch_bounds__(256)
void init_bias_kernel(const float* __restrict__ b, float* __restrict__ H)
{
    int gid = blockIdx.x * 256 + threadIdx.x;
    if (gid >= Nn * F) return;
    int j = gid & (F - 1);
    H[gid] = b[j] + b[F + j] + b[2 * F + j] + b[3 * F + j];
}

// Y = (op(X) * nrm[row]) @ W,  X:[Nn,128], W:[128,BN], op = optional ReLU.
// BM=128, BK=64, 256 threads, per-thread 8 x TN tile (TN = BN/16).
template<int BN>
__global__ __launch_bounds__(256)
void gemm_norm_kernel(const float* __restrict__ X, const float* __restrict__ nrm,
                      const float* __restrict__ W, float* __restrict__ Y,
                      int relu)
{
    constexpr int K = 128, BM = 128, BK = 64;
    constexpr int TN = BN / 16;
    constexpr int LDA = BK + 4;   // 68 floats: float4-aligned rows
    __shared__ float As[BM * LDA];
    __shared__ float Bs[BK * BN];
    const int tid = threadIdx.x;
    const int ty = tid >> 4, tx = tid & 15;
    const int row0 = blockIdx.x * BM;

    float acc[8][TN];
    #pragma unroll
    for (int i = 0; i < 8; ++i)
        #pragma unroll
        for (int j = 0; j < TN; ++j) acc[i][j] = 0.f;

    for (int ko = 0; ko < K; ko += BK) {
        // stage A tile (BM x BK), fused relu+row-norm
        #pragma unroll
        for (int i = 0; i < 8; ++i) {
            int m = (tid >> 4) + i * 16;
            int k = (tid & 15) * 4;
            int g = row0 + m;
            float4 v = make_float4(0.f, 0.f, 0.f, 0.f);
            if (g < Nn) {
                v = *reinterpret_cast<const float4*>(X + (size_t)g * K + ko + k);
                if (relu) {
                    v.x = fmaxf(v.x, 0.f); v.y = fmaxf(v.y, 0.f);
                    v.z = fmaxf(v.z, 0.f); v.w = fmaxf(v.w, 0.f);
                }
                float s = nrm[g];
                v.x *= s; v.y *= s; v.z *= s; v.w *= s;
            }
            *reinterpret_cast<float4*>(&As[m * LDA + k]) = v;
        }
        // stage B tile (BK x BN), straight copy
        #pragma unroll
        for (int i = 0; i < (BK * BN) / 1024; ++i) {
            int idx = tid + i * 256;            // float4 index
            int k = idx / (BN / 4);
            int n = (idx % (BN / 4)) * 4;
            *reinterpret_cast<float4*>(&Bs[k * BN + n]) =
                *reinterpret_cast<const float4*>(W + (size_t)(ko + k) * BN + n);
        }
        __syncthreads();
        #pragma unroll
        for (int k = 0; k < BK; k += 4) {
            float4 a4[8];
            #pragma unroll
            for (int i = 0; i < 8; ++i)
                a4[i] = *reinterpret_cast<const float4*>(&As[(ty * 8 + i) * LDA + k]);
            #pragma unroll
            for (int kk = 0; kk < 4; ++kk) {
                float b[TN];
                #pragma unroll
                for (int j = 0; j < TN; j += 4) {
                    float4 bv = *reinterpret_cast<const float4*>(&Bs[(k + kk) * BN + tx * TN + j]);
                    b[j] = bv.x; b[j + 1] = bv.y; b[j + 2] = bv.z; b[j + 3] = bv.w;
                }
                #pragma unroll
                for (int i = 0; i < 8; ++i) {
                    float av = (kk == 0) ? a4[i].x : (kk == 1) ? a4[i].y
                             : (kk == 2) ? a4[i].z : a4[i].w;
                    #pragma unroll
                    for (int j = 0; j < TN; ++j)
                        acc[i][j] = fmaf(av, b[j], acc[i][j]);
                }
            }
        }
        __syncthreads();
    }
    #pragma unroll
    for (int i = 0; i < 8; ++i) {
        int g = row0 + ty * 8 + i;
        if (g < Nn) {
            #pragma unroll
            for (int j = 0; j < TN; j += 4) {
                float4 v = make_float4(acc[i][j], acc[i][j + 1], acc[i][j + 2], acc[i][j + 3]);
                *reinterpret_cast<float4*>(Y + (size_t)g * BN + tx * TN + j) = v;
            }
        }
    }
}

// H[dst] += norm_dst[dst] * Y[src]   (F floats per edge, 4 per thread)
template<int F>
__global__ __launch_bounds__(256)
void scatter_add_kernel(const float* __restrict__ Y, const int* __restrict__ src,
                        const int* __restrict__ dst, const float* __restrict__ nrm,
                        float* __restrict__ H)
{
    constexpr int C = F / 4;
    int gid = blockIdx.x * 256 + threadIdx.x;
    if (gid >= Ee * C) return;
    int e = gid / C;                 // C is power of 2 -> shift
    int c = (gid - e * C) * 4;
    int s = src[e], d = dst[e];
    float nd = nrm[d];
    float4 v = *reinterpret_cast<const float4*>(Y + (size_t)s * F + c);
    float* o = H + (size_t)d * F + c;
    unsafeAtomicAdd(o + 0, v.x * nd);
    unsafeAtomicAdd(o + 1, v.y * nd);
    unsafeAtomicAdd(o + 2, v.z * nd);
    unsafeAtomicAdd(o + 3, v.w * nd);
}

extern "C" void kernel_launch(void* const* d_in, const int* in_sizes, int n_in,
                              void* d_out, int out_size, void* d_ws, size_t ws_size,
                              hipStream_t stream)
{
    const float* x  = (const float*)d_in[0];
    const int* esrc = (const int*)d_in[1];
    const int* edst = (const int*)d_in[2];
    const float* W1 = (const float*)d_in[3];
    const float* b1 = (const float*)d_in[4];
    const float* W2 = (const float*)d_in[5];
    const float* b2 = (const float*)d_in[6];
    float* out = (float*)d_out;

    // workspace layout
    char* ws = (char*)d_ws;
    unsigned* deg = (unsigned*)ws;                            // [2][R][N] u32
    float* nrm = (float*)(ws + (size_t)2 * Rr * Nn * 4);      // [2][R][N] f32
    float* h   = (float*)(ws + (size_t)4 * Rr * Nn * 4);      // [N][128]
    float* y   = (float*)(ws + (size_t)4 * Rr * Nn * 4 + (size_t)Nn * 128 * 4); // [N][128]
    const float* nsrc = nrm;
    const float* ndst = nrm + (size_t)Rr * Nn;

    hipMemsetAsync(deg, 0, (size_t)2 * Rr * Nn * 4, stream);
    count_deg_kernel<<<(Rr * Ee + 255) / 256, 256, 0, stream>>>(esrc, edst, deg, deg + (size_t)Rr * Nn);
    make_norms_kernel<<<(2 * Rr * Nn + 255) / 256, 256, 0, stream>>>(deg, nrm);

    // ---- layer 1: h = relu( sum_r scatter_r( (x*nsrc_r)@W1_r ) * ndst_r + sum_r b1_r )
    init_bias_kernel<128><<<(Nn * 128 + 255) / 256, 256, 0, stream>>>(b1, h);
    int gb = (Nn + 127) / 128;
    for (int r = 0; r < Rr; ++r) {
        gemm_norm_kernel<128><<<gb, 256, 0, stream>>>(x, nsrc + (size_t)r * Nn,
                                                      W1 + (size_t)r * 128 * 128, y, 0);
        scatter_add_kernel<128><<<(Ee * 32 + 255) / 256, 256, 0, stream>>>(
            y, esrc + (size_t)r * Ee, edst + (size_t)r * Ee, ndst + (size_t)r * Nn, h);
    }

    // ---- layer 2: out = sum_r scatter_r( (relu(h)*nsrc_r)@W2_r ) * ndst_r + sum_r b2_r
    init_bias_kernel<64><<<(Nn * 64 + 255) / 256, 256, 0, stream>>>(b2, out);
    for (int r = 0; r < Rr; ++r) {
        gemm_norm_kernel<64><<<gb, 256, 0, stream>>>(h, nsrc + (size_t)r * Nn,
                                                     W2 + (size_t)r * 128 * 64, y, 1);
        scatter_add_kernel<64><<<(Ee * 16 + 255) / 256, 256, 0, stream>>>(
            y, esrc + (size_t)r * Ee, edst + (size_t)r * Ee, ndst + (size_t)r * Nn, out);
    }
}

// Round 2
// 1062.004 us; speedup vs baseline: 5.4259x; 5.4259x over previous
//
#include <hip/hip_runtime.h>

// RGCN: 2-layer, R=4 relations, N=100000, E=500000/rel, 128->128->64.
// Round 2: GEMM-first per relation, then CSR-by-dst GATHER (no f32 atomics).

constexpr int Nn  = 100000;
constexpr int Rr  = 4;
constexpr int Ee  = 500000;
constexpr int TOT = Rr * Nn;                 // 400000 degree entries per side
constexpr int NB1 = 1024;                    // scan blocks
constexpr int CH  = (TOT + NB1 - 1) / NB1;   // 391 elements per scan block

__global__ __launch_bounds__(256)
void count_deg_kernel(const int* __restrict__ src, const int* __restrict__ dst,
                      unsigned* __restrict__ dsrc, unsigned* __restrict__ ddst)
{
    int gid = blockIdx.x * 256 + threadIdx.x;
    if (gid >= Rr * Ee) return;
    int r = gid / Ee;
    int base = r * Nn;
    atomicAdd(&dsrc[base + src[gid]], 1u);
    atomicAdd(&ddst[base + dst[gid]], 1u);
}

__global__ __launch_bounds__(256)
void make_norms_kernel(const unsigned* __restrict__ deg, float* __restrict__ nrm)
{
    int gid = blockIdx.x * 256 + threadIdx.x;
    if (gid >= 2 * TOT) return;
    unsigned d = deg[gid];
    nrm[gid] = rsqrtf((float)(d > 0u ? d : 1u));
}

// ---- 3-kernel exclusive scan of the dst-degree array (TOT entries) ----
__global__ __launch_bounds__(256)
void scan1_kernel(const unsigned* __restrict__ deg, unsigned* __restrict__ partial)
{
    __shared__ unsigned s[256];
    int b = blockIdx.x, t = threadIdx.x;
    int start = b * CH;
    int n = TOT - start; if (n > CH) n = CH;
    unsigned sum = 0;
    for (int i = t; i < n; i += 256) sum += deg[start + i];
    s[t] = sum; __syncthreads();
    for (int d = 128; d > 0; d >>= 1) {
        if (t < d) s[t] += s[t + d];
        __syncthreads();
    }
    if (t == 0) partial[b] = s[0];
}

__global__ __launch_bounds__(1024)
void scan2_kernel(unsigned* __restrict__ partial, unsigned* __restrict__ rowptr)
{
    __shared__ unsigned s[NB1];
    int t = threadIdx.x;
    unsigned orig = partial[t];
    s[t] = orig; __syncthreads();
    for (int d = 1; d < NB1; d <<= 1) {
        unsigned v = (t >= d) ? s[t - d] : 0u;
        __syncthreads();
        s[t] += v;
        __syncthreads();
    }
    partial[t] = s[t] - orig;                  // exclusive block base
    if (t == 0) rowptr[TOT] = (unsigned)(Rr * Ee);  // sentinel
}

__global__ __launch_bounds__(256)
void scan3_kernel(const unsigned* __restrict__ deg, const unsigned* __restrict__ base,
                  unsigned* __restrict__ rowptr)
{
    __shared__ unsigned s[CH];
    int b = blockIdx.x, t = threadIdx.x;
    int start = b * CH;
    int n = TOT - start; if (n > CH) n = CH;
    if (n <= 0) return;
    for (int i = t; i < n; i += 256) s[i] = deg[start + i];
    __syncthreads();
    if (t == 0) {
        unsigned run = base[b];
        for (int i = 0; i < n; ++i) { unsigned v = s[i]; s[i] = run; run += v; }
    }
    __syncthreads();
    for (int i = t; i < n; i += 256) rowptr[start + i] = s[i];
}

// csr_src[pos] = src for each edge, grouped by (relation, dst)
__global__ __launch_bounds__(256)
void fill_csr_kernel(const int* __restrict__ src, const int* __restrict__ dst,
                     const unsigned* __restrict__ rowptr, unsigned* __restrict__ cursor,
                     int* __restrict__ csr)
{
    int gid = blockIdx.x * 256 + threadIdx.x;
    if (gid >= Rr * Ee) return;
    int r = gid / Ee;
    int idx = r * Nn + dst[gid];
    unsigned pos = rowptr[idx] + atomicAdd(&cursor[idx], 1u);
    csr[pos] = src[gid];
}

__global__ void bsum_kernel(const float* __restrict__ b1, const float* __restrict__ b2,
                            float* __restrict__ bs1, float* __restrict__ bs2)
{
    int t = threadIdx.x;
    if (t < 128) bs1[t] = b1[t] + b1[128 + t] + b1[256 + t] + b1[384 + t];
    if (t < 64)  bs2[t] = b2[t] + b2[64 + t] + b2[128 + t] + b2[192 + t];
}

// Y = (op(X) * nrm[row]) @ W for relation blockIdx.y. X:[Nn,128], W:[128,BN].
template<int BN>
__global__ __launch_bounds__(256)
void gemm_norm_kernel(const float* __restrict__ X, const float* nrm_,
                      const float* W_, float* Y_, int relu)
{
    constexpr int K = 128, BM = 128, BK = 64;
    constexpr int TN = BN / 16;
    constexpr int LDA = BK + 4;
    const int rel = blockIdx.y;
    const float* __restrict__ nrm = nrm_ + (size_t)rel * Nn;
    const float* __restrict__ W   = W_   + (size_t)rel * K * BN;
    float* __restrict__ Y         = Y_   + (size_t)rel * Nn * BN;

    __shared__ float As[BM * LDA];
    __shared__ float Bs[BK * BN];
    const int tid = threadIdx.x;
    const int ty = tid >> 4, tx = tid & 15;
    const int row0 = blockIdx.x * BM;

    float acc[8][TN];
    #pragma unroll
    for (int i = 0; i < 8; ++i)
        #pragma unroll
        for (int j = 0; j < TN; ++j) acc[i][j] = 0.f;

    for (int ko = 0; ko < K; ko += BK) {
        #pragma unroll
        for (int i = 0; i < 8; ++i) {
            int m = (tid >> 4) + i * 16;
            int k = (tid & 15) * 4;
            int g = row0 + m;
            float4 v = make_float4(0.f, 0.f, 0.f, 0.f);
            if (g < Nn) {
                v = *reinterpret_cast<const float4*>(X + (size_t)g * K + ko + k);
                if (relu) {
                    v.x = fmaxf(v.x, 0.f); v.y = fmaxf(v.y, 0.f);
                    v.z = fmaxf(v.z, 0.f); v.w = fmaxf(v.w, 0.f);
                }
                float s = nrm[g];
                v.x *= s; v.y *= s; v.z *= s; v.w *= s;
            }
            *reinterpret_cast<float4*>(&As[m * LDA + k]) = v;
        }
        #pragma unroll
        for (int i = 0; i < (BK * BN) / 1024; ++i) {
            int idx = tid + i * 256;
            int k = idx / (BN / 4);
            int n = (idx % (BN / 4)) * 4;
            *reinterpret_cast<float4*>(&Bs[k * BN + n]) =
                *reinterpret_cast<const float4*>(W + (size_t)(ko + k) * BN + n);
        }
        __syncthreads();
        #pragma unroll
        for (int k = 0; k < BK; k += 4) {
            float4 a4[8];
            #pragma unroll
            for (int i = 0; i < 8; ++i)
                a4[i] = *reinterpret_cast<const float4*>(&As[(ty * 8 + i) * LDA + k]);
            #pragma unroll
            for (int kk = 0; kk < 4; ++kk) {
                float b[TN];
                #pragma unroll
                for (int j = 0; j < TN; j += 4) {
                    float4 bv = *reinterpret_cast<const float4*>(&Bs[(k + kk) * BN + tx * TN + j]);
                    b[j] = bv.x; b[j + 1] = bv.y; b[j + 2] = bv.z; b[j + 3] = bv.w;
                }
                #pragma unroll
                for (int i = 0; i < 8; ++i) {
                    float av = (kk == 0) ? a4[i].x : (kk == 1) ? a4[i].y
                             : (kk == 2) ? a4[i].z : a4[i].w;
                    #pragma unroll
                    for (int j = 0; j < TN; ++j)
                        acc[i][j] = fmaf(av, b[j], acc[i][j]);
                }
            }
        }
        __syncthreads();
    }
    #pragma unroll
    for (int i = 0; i < 8; ++i) {
        int g = row0 + ty * 8 + i;
        if (g < Nn) {
            #pragma unroll
            for (int j = 0; j < TN; j += 4) {
                float4 v = make_float4(acc[i][j], acc[i][j + 1], acc[i][j + 2], acc[i][j + 3]);
                *reinterpret_cast<float4*>(Y + (size_t)g * BN + tx * TN + j) = v;
            }
        }
    }
}

// One wave per dst node: H[n] (+)= sum_{r<NR} ndst_r[n] * sum_{e in csr(r,n)} Y_r[src[e]]
// rowptr/ndst pre-offset by r0*Nn by caller; Y holds NR relations at stride Nn*F.
template<int F, int NR>
__global__ __launch_bounds__(256)
void gather_kernel(const float* __restrict__ Y, const unsigned* __restrict__ rowptr,
                   const int* __restrict__ csr, const float* __restrict__ ndst,
                   const float* __restrict__ bsum, float* __restrict__ H, int accumulate)
{
    constexpr int VF = F / 64;           // floats per lane (2 for F=128, 1 for F=64)
    int wid  = (blockIdx.x * 256 + threadIdx.x) >> 6;
    int lane = threadIdx.x & 63;
    if (wid >= Nn) return;

    float tot[VF];
    #pragma unroll
    for (int v = 0; v < VF; ++v) tot[v] = 0.f;

    #pragma unroll
    for (int r = 0; r < NR; ++r) {
        const float* yr = Y + (size_t)r * Nn * F;
        unsigned e  = rowptr[r * Nn + wid];
        unsigned e1 = rowptr[r * Nn + wid + 1];
        float acc[VF];
        #pragma unroll
        for (int v = 0; v < VF; ++v) acc[v] = 0.f;
        // 2-edge unroll for memory-level parallelism
        for (; e + 2 <= e1; e += 2) {
            int sA = csr[e], sB = csr[e + 1];
            if constexpr (VF == 2) {
                float2 vA = *reinterpret_cast<const float2*>(yr + (size_t)sA * F + lane * 2);
                float2 vB = *reinterpret_cast<const float2*>(yr + (size_t)sB * F + lane * 2);
                acc[0] += vA.x + vB.x;
                acc[1] += vA.y + vB.y;
            } else {
                acc[0] += yr[(size_t)sA * F + lane] + yr[(size_t)sB * F + lane];
            }
        }
        if (e < e1) {
            int sA = csr[e];
            if constexpr (VF == 2) {
                float2 vA = *reinterpret_cast<const float2*>(yr + (size_t)sA * F + lane * 2);
                acc[0] += vA.x; acc[1] += vA.y;
            } else {
                acc[0] += yr[(size_t)sA * F + lane];
            }
        }
        float nd = ndst[r * Nn + wid];
        #pragma unroll
        for (int v = 0; v < VF; ++v) tot[v] += nd * acc[v];
    }

    float* hp = H + (size_t)wid * F + lane * VF;
    if (accumulate) {
        #pragma unroll
        for (int v = 0; v < VF; ++v) tot[v] += hp[v];
    } else {
        #pragma unroll
        for (int v = 0; v < VF; ++v) tot[v] += bsum[lane * VF + v];
    }
    if constexpr (VF == 2) *reinterpret_cast<float2*>(hp) = make_float2(tot[0], tot[1]);
    else                   hp[0] = tot[0];
}

extern "C" void kernel_launch(void* const* d_in, const int* in_sizes, int n_in,
                              void* d_out, int out_size, void* d_ws, size_t ws_size,
                              hipStream_t stream)
{
    const float* x  = (const float*)d_in[0];
    const int* esrc = (const int*)d_in[1];
    const int* edst = (const int*)d_in[2];
    const float* W1 = (const float*)d_in[3];
    const float* b1 = (const float*)d_in[4];
    const float* W2 = (const float*)d_in[5];
    const float* b2 = (const float*)d_in[6];
    float* out = (float*)d_out;

    // ---- workspace layout ----
    char* ws = (char*)d_ws;
    size_t off = 0;
    auto alloc = [&](size_t bytes) { char* p = ws + off; off += (bytes + 255) & ~(size_t)255; return p; };
    unsigned* deg     = (unsigned*)alloc((size_t)2 * TOT * 4);   // [src|dst][R][N]
    float*    nrm     = (float*)   alloc((size_t)2 * TOT * 4);
    unsigned* rowptr  = (unsigned*)alloc((size_t)(TOT + 1) * 4);
    unsigned* cursor  = (unsigned*)alloc((size_t)TOT * 4);
    unsigned* partial = (unsigned*)alloc((size_t)NB1 * 4);
    float*    bs1     = (float*)   alloc(128 * 4);
    float*    bs2     = (float*)   alloc(64 * 4);
    int*      csr     = (int*)     alloc((size_t)Rr * Ee * 4);
    float*    h       = (float*)   alloc((size_t)Nn * 128 * 4);
    size_t yslot = (size_t)Nn * 128 * 4;
    size_t avail = (ws_size > off) ? ws_size - off : 0;
    int slots = (avail >= 2 * yslot) ? 2 : 1;     // relations per pass
    float* Y = (float*)alloc((size_t)slots * yslot);

    const float* nsrc = nrm;
    const float* ndst = nrm + TOT;
    unsigned* ddst = deg + TOT;

    // ---- graph preprocessing (every call; deterministic work) ----
    hipMemsetAsync(deg, 0, (size_t)2 * TOT * 4, stream);
    hipMemsetAsync(cursor, 0, (size_t)TOT * 4, stream);
    count_deg_kernel<<<(Rr * Ee + 255) / 256, 256, 0, stream>>>(esrc, edst, deg, ddst);
    make_norms_kernel<<<(2 * TOT + 255) / 256, 256, 0, stream>>>(deg, nrm);
    scan1_kernel<<<NB1, 256, 0, stream>>>(ddst, partial);
    scan2_kernel<<<1, NB1, 0, stream>>>(partial, rowptr);
    scan3_kernel<<<NB1, 256, 0, stream>>>(ddst, partial, rowptr);
    fill_csr_kernel<<<(Rr * Ee + 255) / 256, 256, 0, stream>>>(esrc, edst, rowptr, cursor, csr);
    bsum_kernel<<<1, 128, 0, stream>>>(b1, b2, bs1, bs2);

    const int gb = (Nn + 127) / 128;            // GEMM row blocks
    const int gw = (Nn * 64 + 255) / 256;       // gather blocks (4 waves each)

    // ---- layer 1: h = sum_r ndst_r * gather_r( (x*nsrc_r)@W1_r ) + bsum1 ----
    for (int r0 = 0; r0 < Rr; r0 += slots) {
        gemm_norm_kernel<128><<<dim3(gb, slots), 256, 0, stream>>>(
            x, nsrc + (size_t)r0 * Nn, W1 + (size_t)r0 * 128 * 128, Y, 0);
        if (slots == 2)
            gather_kernel<128, 2><<<gw, 256, 0, stream>>>(
                Y, rowptr + (size_t)r0 * Nn, csr, ndst + (size_t)r0 * Nn, bs1, h, r0 > 0);
        else
            gather_kernel<128, 1><<<gw, 256, 0, stream>>>(
                Y, rowptr + (size_t)r0 * Nn, csr, ndst + (size_t)r0 * Nn, bs1, h, r0 > 0);
    }

    // ---- layer 2: out = sum_r ndst_r * gather_r( (relu(h)*nsrc_r)@W2_r ) + bsum2 ----
    for (int r0 = 0; r0 < Rr; r0 += slots) {
        gemm_norm_kernel<64><<<dim3(gb, slots), 256, 0, stream>>>(
            h, nsrc + (size_t)r0 * Nn, W2 + (size_t)r0 * 128 * 64, Y, 1);
        if (slots == 2)
            gather_kernel<64, 2><<<gw, 256, 0, stream>>>(
                Y, rowptr + (size_t)r0 * Nn, csr, ndst + (size_t)r0 * Nn, bs2, out, r0 > 0);
        else
            gather_kernel<64, 1><<<gw, 256, 0, stream>>>(
                Y, rowptr + (size_t)r0 * Nn, csr, ndst + (size_t)r0 * Nn, bs2, out, r0 > 0);
    }
}

// Round 3
// 800.930 us; speedup vs baseline: 7.1946x; 1.3260x over previous
//
#include <hip/hip_runtime.h>

// RGCN: 2-layer, R=4, N=100000, E=500000/rel, 128->128->64.
// Round 3: norms folded into per-edge weights; GEMM on MFMA via bf16 hi/lo
// split (3 products, fp32-quality); CSR gather (no f32 atomics).

constexpr int Nn  = 100000;
constexpr int Rr  = 4;
constexpr int Ee  = 500000;
constexpr int TOT = Rr * Nn;
constexpr int NP  = 100096;            // Nn padded to 128 rows
constexpr int NPB = NP / 128;          // 782 row-blocks
constexpr int NB1 = 1024;
constexpr int CH  = (TOT + NB1 - 1) / NB1;

typedef short bf16x8 __attribute__((ext_vector_type(8)));
typedef float f32x4  __attribute__((ext_vector_type(4)));

__device__ __forceinline__ unsigned short f2bf(float f) {
    unsigned u = __builtin_bit_cast(unsigned, f);
    u = u + 0x7FFFu + ((u >> 16) & 1u);          // round-to-nearest-even
    return (unsigned short)(u >> 16);
}
__device__ __forceinline__ float bf2f(unsigned short h) {
    unsigned u = ((unsigned)h) << 16;
    return __builtin_bit_cast(float, u);
}

// ---------------- graph preprocessing ----------------
__global__ __launch_bounds__(256)
void count_deg_kernel(const int* __restrict__ src, const int* __restrict__ dst,
                      unsigned* __restrict__ dsrc, unsigned* __restrict__ ddst)
{
    int gid = blockIdx.x * 256 + threadIdx.x;
    if (gid >= Rr * Ee) return;
    int r = gid / Ee;
    int base = r * Nn;
    atomicAdd(&dsrc[base + src[gid]], 1u);
    atomicAdd(&ddst[base + dst[gid]], 1u);
}

__global__ __launch_bounds__(256)
void make_norms_kernel(const unsigned* __restrict__ deg, float* __restrict__ nrm)
{
    int gid = blockIdx.x * 256 + threadIdx.x;
    if (gid >= 2 * TOT) return;
    unsigned d = deg[gid];
    nrm[gid] = rsqrtf((float)(d > 0u ? d : 1u));
}

__global__ __launch_bounds__(256)
void scan1_kernel(const unsigned* __restrict__ deg, unsigned* __restrict__ partial)
{
    __shared__ unsigned s[256];
    int b = blockIdx.x, t = threadIdx.x;
    int start = b * CH;
    int n = TOT - start; if (n > CH) n = CH;
    unsigned sum = 0;
    for (int i = t; i < n; i += 256) sum += deg[start + i];
    s[t] = sum; __syncthreads();
    for (int d = 128; d > 0; d >>= 1) {
        if (t < d) s[t] += s[t + d];
        __syncthreads();
    }
    if (t == 0) partial[b] = s[0];
}

__global__ __launch_bounds__(1024)
void scan2_kernel(unsigned* __restrict__ partial, unsigned* __restrict__ rowptr)
{
    __shared__ unsigned s[NB1];
    int t = threadIdx.x;
    unsigned orig = partial[t];
    s[t] = orig; __syncthreads();
    for (int d = 1; d < NB1; d <<= 1) {
        unsigned v = (t >= d) ? s[t - d] : 0u;
        __syncthreads();
        s[t] += v;
        __syncthreads();
    }
    partial[t] = s[t] - orig;
    if (t == 0) rowptr[TOT] = (unsigned)(Rr * Ee);
}

__global__ __launch_bounds__(256)
void scan3_kernel(const unsigned* __restrict__ deg, const unsigned* __restrict__ base,
                  unsigned* __restrict__ rowptr)
{
    __shared__ unsigned s[CH];
    int b = blockIdx.x, t = threadIdx.x;
    int start = b * CH;
    int n = TOT - start; if (n > CH) n = CH;
    if (n <= 0) return;
    for (int i = t; i < n; i += 256) s[i] = deg[start + i];
    __syncthreads();
    if (t == 0) {
        unsigned run = base[b];
        for (int i = 0; i < n; ++i) { unsigned v = s[i]; s[i] = run; run += v; }
    }
    __syncthreads();
    for (int i = t; i < n; i += 256) rowptr[start + i] = s[i];
}

// csr[pos]=src, wgt[pos]=nsrc[src]*ndst[dst], grouped by (relation,dst)
__global__ __launch_bounds__(256)
void fill_csr_kernel(const int* __restrict__ src, const int* __restrict__ dst,
                     const unsigned* __restrict__ rowptr, unsigned* __restrict__ cursor,
                     const float* __restrict__ nsrc, const float* __restrict__ ndst,
                     int* __restrict__ csr, float* __restrict__ wgt)
{
    int gid = blockIdx.x * 256 + threadIdx.x;
    if (gid >= Rr * Ee) return;
    int r = gid / Ee;
    int s = src[gid], d = dst[gid];
    int idx = r * Nn + d;
    unsigned pos = rowptr[idx] + atomicAdd(&cursor[idx], 1u);
    csr[pos] = s;
    wgt[pos] = nsrc[r * Nn + s] * ndst[r * Nn + d];
}

__global__ void bsum_kernel(const float* __restrict__ b1, const float* __restrict__ b2,
                            float* __restrict__ bs1, float* __restrict__ bs2)
{
    int t = threadIdx.x;
    if (t < 128) bs1[t] = b1[t] + b1[128 + t] + b1[256 + t] + b1[384 + t];
    if (t < 64)  bs2[t] = b2[t] + b2[64 + t] + b2[128 + t] + b2[192 + t];
}

// ---------------- bf16 hi/lo conversions ----------------
// W1[r][k][n] -> w1h/w1l [r][n][k]; W2 likewise (transposed for B-frag reads)
__global__ __launch_bounds__(256)
void convw_kernel(const float* __restrict__ W1, const float* __restrict__ W2,
                  short* __restrict__ w1h, short* __restrict__ w1l,
                  short* __restrict__ w2h, short* __restrict__ w2l)
{
    int gid = blockIdx.x * 256 + threadIdx.x;
    if (gid < 4 * 128 * 128) {
        int r = gid >> 14, rem = gid & 16383, n = rem >> 7, k = rem & 127;
        float v = W1[(r << 14) + k * 128 + n];
        unsigned short h = f2bf(v);
        unsigned short l = f2bf(v - bf2f(h));
        w1h[(r << 14) + n * 128 + k] = (short)h;
        w1l[(r << 14) + n * 128 + k] = (short)l;
    } else {
        int g2 = gid - 65536;
        if (g2 >= 4 * 64 * 128) return;
        int r = g2 >> 13, rem = g2 & 8191, n = rem >> 7, k = rem & 127;
        float v = W2[(r << 13) + k * 64 + n];
        unsigned short h = f2bf(v);
        unsigned short l = f2bf(v - bf2f(h));
        w2h[(r << 13) + n * 128 + k] = (short)h;
        w2l[(r << 13) + n * 128 + k] = (short)l;
    }
}

// X[Nn][128] f32 -> Xh/Xl [NP][128] bf16 (pad rows zero), optional relu
template<int RELU>
__global__ __launch_bounds__(256)
void convx_kernel(const float* __restrict__ X, short* __restrict__ Xh,
                  short* __restrict__ Xl)
{
    size_t base = ((size_t)blockIdx.x * 256 + threadIdx.x) * 8;
    if (base >= (size_t)NP * 128) return;
    bf16x8 hv, lv;
    #pragma unroll
    for (int i = 0; i < 8; ++i) { hv[i] = 0; lv[i] = 0; }
    if (base < (size_t)Nn * 128) {
        float4 a = *reinterpret_cast<const float4*>(X + base);
        float4 b = *reinterpret_cast<const float4*>(X + base + 4);
        float f[8] = {a.x, a.y, a.z, a.w, b.x, b.y, b.z, b.w};
        #pragma unroll
        for (int i = 0; i < 8; ++i) {
            float v = RELU ? fmaxf(f[i], 0.f) : f[i];
            unsigned short h = f2bf(v);
            hv[i] = (short)h;
            lv[i] = (short)f2bf(v - bf2f(h));
        }
    }
    *reinterpret_cast<bf16x8*>(Xh + base) = hv;
    *reinterpret_cast<bf16x8*>(Xl + base) = lv;
}

// ---------------- MFMA GEMM: Y[:, blockIdx.y*BN ...] = X @ W_rel ----------------
// X = Xh+Xl (bf16 split), W pre-transposed [n][k]. 3-product accumulation.
template<int BN>
__global__ __launch_bounds__(256)
void gemm_kernel(const short* __restrict__ Xh, const short* __restrict__ Xl,
                 const short* __restrict__ WhT_, const short* __restrict__ WlT_,
                 float* __restrict__ Y_, int CW)
{
    constexpr int BM = 128, BKp = 40;            // 32 k + 8 pad (80B rows)
    constexpr int MFR = (BN == 128) ? 4 : 2;     // 16-row frags per wave
    constexpr int NFR = 4;                       // 64 cols per wave
    const short* WhT = WhT_ + (size_t)blockIdx.y * (BN * 128);
    const short* WlT = WlT_ + (size_t)blockIdx.y * (BN * 128);
    float* Y = Y_ + (size_t)blockIdx.y * BN;

    __shared__ __align__(16) short Ah[BM * BKp], Al[BM * BKp];
    __shared__ __align__(16) short Bh[BN * BKp], Bl[BN * BKp];

    const int tid = threadIdx.x;
    const int lane = tid & 63, wid = tid >> 6;
    const int lr = lane & 15, lg = lane >> 4;
    const int wm0 = (BN == 128) ? (wid >> 1) * 64 : wid * 32;
    const int wn0 = (BN == 128) ? (wid & 1) * 64 : 0;
    const int row0 = blockIdx.x * BM;

    f32x4 acc[MFR][NFR];
    #pragma unroll
    for (int m = 0; m < MFR; ++m)
        #pragma unroll
        for (int n = 0; n < NFR; ++n)
            #pragma unroll
            for (int j = 0; j < 4; ++j) acc[m][n][j] = 0.f;

    const int sr = tid >> 1;            // staged row (0..127)
    const int sko = (tid & 1) * 16;     // k segment

    for (int ks = 0; ks < 4; ++ks) {
        // stage A (hi+lo), 16 bf16 per thread per array
        size_t ga = (size_t)(row0 + sr) * 128 + ks * 32 + sko;
        *reinterpret_cast<bf16x8*>(&Ah[sr * BKp + sko])     = *reinterpret_cast<const bf16x8*>(&Xh[ga]);
        *reinterpret_cast<bf16x8*>(&Ah[sr * BKp + sko + 8]) = *reinterpret_cast<const bf16x8*>(&Xh[ga + 8]);
        *reinterpret_cast<bf16x8*>(&Al[sr * BKp + sko])     = *reinterpret_cast<const bf16x8*>(&Xl[ga]);
        *reinterpret_cast<bf16x8*>(&Al[sr * BKp + sko + 8]) = *reinterpret_cast<const bf16x8*>(&Xl[ga + 8]);
        // stage B (hi+lo); for BN=64 only first 128 threads
        if (BN == 128 || tid < 128) {
            size_t gb = (size_t)sr * 128 + ks * 32 + sko;
            *reinterpret_cast<bf16x8*>(&Bh[sr * BKp + sko])     = *reinterpret_cast<const bf16x8*>(&WhT[gb]);
            *reinterpret_cast<bf16x8*>(&Bh[sr * BKp + sko + 8]) = *reinterpret_cast<const bf16x8*>(&WhT[gb + 8]);
            *reinterpret_cast<bf16x8*>(&Bl[sr * BKp + sko])     = *reinterpret_cast<const bf16x8*>(&WlT[gb]);
            *reinterpret_cast<bf16x8*>(&Bl[sr * BKp + sko + 8]) = *reinterpret_cast<const bf16x8*>(&WlT[gb + 8]);
        }
        __syncthreads();

        bf16x8 bh[NFR], bl[NFR];
        #pragma unroll
        for (int n = 0; n < NFR; ++n) {
            bh[n] = *reinterpret_cast<const bf16x8*>(&Bh[(wn0 + n * 16 + lr) * BKp + lg * 8]);
            bl[n] = *reinterpret_cast<const bf16x8*>(&Bl[(wn0 + n * 16 + lr) * BKp + lg * 8]);
        }
        #pragma unroll
        for (int m = 0; m < MFR; ++m) {
            bf16x8 ah = *reinterpret_cast<const bf16x8*>(&Ah[(wm0 + m * 16 + lr) * BKp + lg * 8]);
            bf16x8 al = *reinterpret_cast<const bf16x8*>(&Al[(wm0 + m * 16 + lr) * BKp + lg * 8]);
            #pragma unroll
            for (int n = 0; n < NFR; ++n) {
                acc[m][n] = __builtin_amdgcn_mfma_f32_16x16x32_bf16(ah, bh[n], acc[m][n], 0, 0, 0);
                acc[m][n] = __builtin_amdgcn_mfma_f32_16x16x32_bf16(ah, bl[n], acc[m][n], 0, 0, 0);
                acc[m][n] = __builtin_amdgcn_mfma_f32_16x16x32_bf16(al, bh[n], acc[m][n], 0, 0, 0);
            }
        }
        __syncthreads();
    }

    // epilogue: C/D layout col=lane&15, row=(lane>>4)*4+j  [m89]
    #pragma unroll
    for (int m = 0; m < MFR; ++m)
        #pragma unroll
        for (int n = 0; n < NFR; ++n) {
            int col = wn0 + n * 16 + lr;
            int rb = row0 + wm0 + m * 16 + lg * 4;
            #pragma unroll
            for (int j = 0; j < 4; ++j)
                Y[(size_t)(rb + j) * CW + col] = acc[m][n][j];
        }
}

// ---------------- CSR gather: H[n] (+)= sum_r sum_e w_e * Y_r[src_e] ----------------
template<int F, int NR>
__global__ __launch_bounds__(256)
void gather_kernel(const float* __restrict__ Y, const unsigned* __restrict__ rowptr,
                   const int* __restrict__ csr, const float* __restrict__ wgt,
                   const float* __restrict__ bsum, float* __restrict__ H, int accumulate)
{
    constexpr int VF = F / 64;
    constexpr int CW = NR * F;
    int wid = (blockIdx.x * 256 + threadIdx.x) >> 6;
    int lane = threadIdx.x & 63;
    if (wid >= Nn) return;
    float t0 = 0.f, t1 = 0.f;
    #pragma unroll
    for (int rl = 0; rl < NR; ++rl) {
        const float* yr = Y + rl * F;
        unsigned e  = rowptr[rl * Nn + wid];
        unsigned e1 = rowptr[rl * Nn + wid + 1];
        for (; e + 2 <= e1; e += 2) {
            int sA = csr[e];     float wA = wgt[e];
            int sB = csr[e + 1]; float wB = wgt[e + 1];
            if constexpr (VF == 2) {
                float2 vA = *reinterpret_cast<const float2*>(yr + (size_t)sA * CW + lane * 2);
                float2 vB = *reinterpret_cast<const float2*>(yr + (size_t)sB * CW + lane * 2);
                t0 += wA * vA.x + wB * vB.x;
                t1 += wA * vA.y + wB * vB.y;
            } else {
                t0 += wA * yr[(size_t)sA * CW + lane] + wB * yr[(size_t)sB * CW + lane];
            }
        }
        if (e < e1) {
            int sA = csr[e]; float wA = wgt[e];
            if constexpr (VF == 2) {
                float2 vA = *reinterpret_cast<const float2*>(yr + (size_t)sA * CW + lane * 2);
                t0 += wA * vA.x; t1 += wA * vA.y;
            } else {
                t0 += wA * yr[(size_t)sA * CW + lane];
            }
        }
    }
    float* hp = H + (size_t)wid * F + lane * VF;
    if (accumulate) {
        t0 += hp[0]; if (VF == 2) t1 += hp[1];
    } else {
        t0 += bsum[lane * VF]; if (VF == 2) t1 += bsum[lane * VF + 1];
    }
    if constexpr (VF == 2) *reinterpret_cast<float2*>(hp) = make_float2(t0, t1);
    else hp[0] = t0;
}

extern "C" void kernel_launch(void* const* d_in, const int* in_sizes, int n_in,
                              void* d_out, int out_size, void* d_ws, size_t ws_size,
                              hipStream_t stream)
{
    const float* x  = (const float*)d_in[0];
    const int* esrc = (const int*)d_in[1];
    const int* edst = (const int*)d_in[2];
    const float* W1 = (const float*)d_in[3];
    const float* b1 = (const float*)d_in[4];
    const float* W2 = (const float*)d_in[5];
    const float* b2 = (const float*)d_in[6];
    float* out = (float*)d_out;

    // ---- workspace layout ----
    char* ws = (char*)d_ws;
    size_t off = 0;
    auto alloc = [&](size_t bytes) { char* p = ws + off; off += (bytes + 255) & ~(size_t)255; return p; };
    unsigned* deg     = (unsigned*)alloc((size_t)2 * TOT * 4);
    float*    nrm     = (float*)   alloc((size_t)2 * TOT * 4);
    unsigned* rowptr  = (unsigned*)alloc((size_t)(TOT + 1) * 4);
    unsigned* cursor  = (unsigned*)alloc((size_t)TOT * 4);
    unsigned* partial = (unsigned*)alloc((size_t)NB1 * 4);
    float*    bs1     = (float*)   alloc(128 * 4);
    float*    bs2     = (float*)   alloc(64 * 4);
    short*    w1h     = (short*)   alloc((size_t)4 * 128 * 128 * 2);
    short*    w1l     = (short*)   alloc((size_t)4 * 128 * 128 * 2);
    short*    w2h     = (short*)   alloc((size_t)4 * 64 * 128 * 2);
    short*    w2l     = (short*)   alloc((size_t)4 * 64 * 128 * 2);
    int*      csr     = (int*)     alloc((size_t)Rr * Ee * 4);
    float*    wgt     = (float*)   alloc((size_t)Rr * Ee * 4);
    short*    xh      = (short*)   alloc((size_t)NP * 128 * 2);
    short*    xl      = (short*)   alloc((size_t)NP * 128 * 2);
    float*    h       = (float*)   alloc((size_t)NP * 128 * 4);
    size_t ybytes = (size_t)NP * 128 * 4;                   // one 128-col slot
    int slots = (ws_size >= off + 2 * ybytes) ? 2 : 1;      // relations per pass
    float* Y = (float*)alloc((size_t)slots * ybytes);

    const float* nsrc = nrm;
    const float* ndst = nrm + TOT;
    unsigned* ddst = deg + TOT;

    // ---- preprocessing ----
    hipMemsetAsync(deg, 0, (size_t)2 * TOT * 4, stream);
    hipMemsetAsync(cursor, 0, (size_t)TOT * 4, stream);
    count_deg_kernel<<<(Rr * Ee + 255) / 256, 256, 0, stream>>>(esrc, edst, deg, ddst);
    make_norms_kernel<<<(2 * TOT + 255) / 256, 256, 0, stream>>>(deg, nrm);
    scan1_kernel<<<NB1, 256, 0, stream>>>(ddst, partial);
    scan2_kernel<<<1, NB1, 0, stream>>>(partial, rowptr);
    scan3_kernel<<<NB1, 256, 0, stream>>>(ddst, partial, rowptr);
    fill_csr_kernel<<<(Rr * Ee + 255) / 256, 256, 0, stream>>>(
        esrc, edst, rowptr, cursor, nsrc, ndst, csr, wgt);
    bsum_kernel<<<1, 128, 0, stream>>>(b1, b2, bs1, bs2);
    convw_kernel<<<(98304 + 255) / 256, 256, 0, stream>>>(W1, W2, w1h, w1l, w2h, w2l);

    const int cvgrid = (NP * 128 / 8 + 255) / 256;   // 6256
    const int ggrid  = (Nn * 64 + 255) / 256;        // 25000

    // ---- layer 1 ----
    convx_kernel<0><<<cvgrid, 256, 0, stream>>>(x, xh, xl);
    for (int r0 = 0; r0 < Rr; r0 += slots) {
        gemm_kernel<128><<<dim3(NPB, slots), 256, 0, stream>>>(
            xh, xl, w1h + (size_t)r0 * 128 * 128, w1l + (size_t)r0 * 128 * 128, Y, slots * 128);
        if (slots == 2)
            gather_kernel<128, 2><<<ggrid, 256, 0, stream>>>(
                Y, rowptr + (size_t)r0 * Nn, csr, wgt, bs1, h, r0 > 0);
        else
            gather_kernel<128, 1><<<ggrid, 256, 0, stream>>>(
                Y, rowptr + (size_t)r0 * Nn, csr, wgt, bs1, h, r0 > 0);
    }

    // ---- layer 2 ----
    convx_kernel<1><<<cvgrid, 256, 0, stream>>>(h, xh, xl);
    for (int r0 = 0; r0 < Rr; r0 += slots) {
        gemm_kernel<64><<<dim3(NPB, slots), 256, 0, stream>>>(
            xh, xl, w2h + (size_t)r0 * 64 * 128, w2l + (size_t)r0 * 64 * 128, Y, slots * 64);
        if (slots == 2)
            gather_kernel<64, 2><<<ggrid, 256, 0, stream>>>(
                Y, rowptr + (size_t)r0 * Nn, csr, wgt, bs2, out, r0 > 0);
        else
            gather_kernel<64, 1><<<ggrid, 256, 0, stream>>>(
                Y, rowptr + (size_t)r0 * Nn, csr, wgt, bs2, out, r0 > 0);
    }
}

// Round 4
// 688.553 us; speedup vs baseline: 8.3688x; 1.1632x over previous
//
#include <hip/hip_runtime.h>

// RGCN: 2-layer, R=4, N=100000, E=500000/rel, 128->128->64.
// Round 4: sharded degree histogram; packed (src,wgt) CSR; bf16 Y; fused
// 4-relation GEMM+gather per layer with gather-side bias/ReLU/bf16-split.

constexpr int Nn  = 100000;
constexpr int Rr  = 4;
constexpr int Ee  = 500000;
constexpr int RE  = Rr * Ee;
constexpr int TOT = Rr * Nn;
constexpr int NP  = 100096;            // Nn padded to 128 rows
constexpr int NPB = NP / 128;          // 782 row-blocks
constexpr int NB1 = 1024;
constexpr int CH  = (TOT + NB1 - 1) / NB1;
constexpr int SH  = 4;                 // histogram shards per side

typedef short bf16x8 __attribute__((ext_vector_type(8)));
typedef float f32x4  __attribute__((ext_vector_type(4)));

__device__ __forceinline__ unsigned short f2bf(float f) {
    unsigned u = __builtin_bit_cast(unsigned, f);
    u = u + 0x7FFFu + ((u >> 16) & 1u);          // round-to-nearest-even
    return (unsigned short)(u >> 16);
}
__device__ __forceinline__ float bf2f(unsigned short h) {
    unsigned u = ((unsigned)h) << 16;
    return __builtin_bit_cast(float, u);
}
__device__ __forceinline__ float bfbits_lo(unsigned p) {   // low short -> f32
    return __builtin_bit_cast(float, p << 16);
}
__device__ __forceinline__ float bfbits_hi(unsigned p) {   // high short -> f32
    return __builtin_bit_cast(float, p & 0xFFFF0000u);
}

// ---------------- graph preprocessing ----------------
// degS layout: [side(0=src,1=dst)][shard(4)][TOT]
__global__ __launch_bounds__(256)
void count_deg_kernel(const int* __restrict__ src, const int* __restrict__ dst,
                      unsigned* __restrict__ degS)
{
    int gid = blockIdx.x * 256 + threadIdx.x;
    if (gid >= RE) return;
    int r = gid / Ee;
    int sh = threadIdx.x & (SH - 1);
    int base = r * Nn;
    atomicAdd(&degS[(size_t)sh * TOT + base + src[gid]], 1u);
    atomicAdd(&degS[(size_t)(SH + sh) * TOT + base + dst[gid]], 1u);
}

// reduce shards -> norms (both sides) + summed dst-degree for the scan
__global__ __launch_bounds__(256)
void norms_kernel(const unsigned* __restrict__ degS, float* __restrict__ nrm,
                  unsigned* __restrict__ dsum)
{
    int gid = blockIdx.x * 256 + threadIdx.x;
    if (gid >= TOT) return;
    unsigned s = 0, d = 0;
    #pragma unroll
    for (int i = 0; i < SH; ++i) {
        s += degS[(size_t)i * TOT + gid];
        d += degS[(size_t)(SH + i) * TOT + gid];
    }
    nrm[gid]       = rsqrtf((float)(s > 0u ? s : 1u));
    nrm[TOT + gid] = rsqrtf((float)(d > 0u ? d : 1u));
    dsum[gid] = d;
}

__global__ __launch_bounds__(256)
void scan1_kernel(const unsigned* __restrict__ deg, unsigned* __restrict__ partial)
{
    __shared__ unsigned s[256];
    int b = blockIdx.x, t = threadIdx.x;
    int start = b * CH;
    int n = TOT - start; if (n > CH) n = CH;
    unsigned sum = 0;
    for (int i = t; i < n; i += 256) sum += deg[start + i];
    s[t] = sum; __syncthreads();
    for (int d = 128; d > 0; d >>= 1) {
        if (t < d) s[t] += s[t + d];
        __syncthreads();
    }
    if (t == 0) partial[b] = s[0];
}

__global__ __launch_bounds__(1024)
void scan2_kernel(unsigned* __restrict__ partial, unsigned* __restrict__ rowptr)
{
    __shared__ unsigned s[NB1];
    int t = threadIdx.x;
    unsigned orig = partial[t];
    s[t] = orig; __syncthreads();
    for (int d = 1; d < NB1; d <<= 1) {
        unsigned v = (t >= d) ? s[t - d] : 0u;
        __syncthreads();
        s[t] += v;
        __syncthreads();
    }
    partial[t] = s[t] - orig;
    if (t == 0) rowptr[TOT] = (unsigned)RE;
}

__global__ __launch_bounds__(256)
void scan3_kernel(const unsigned* __restrict__ deg, const unsigned* __restrict__ base,
                  unsigned* __restrict__ rowptr)
{
    __shared__ unsigned s[CH];
    int b = blockIdx.x, t = threadIdx.x;
    int start = b * CH;
    int n = TOT - start; if (n > CH) n = CH;
    if (n <= 0) return;
    for (int i = t; i < n; i += 256) s[i] = deg[start + i];
    __syncthreads();
    if (t == 0) {
        unsigned run = base[b];
        for (int i = 0; i < n; ++i) { unsigned v = s[i]; s[i] = run; run += v; }
    }
    __syncthreads();
    for (int i = t; i < n; i += 256) rowptr[start + i] = s[i];
}

// csrw[pos] = {src, bits(nsrc[src]*ndst[dst])}, grouped by (relation,dst)
__global__ __launch_bounds__(256)
void fill_csr_kernel(const int* __restrict__ src, const int* __restrict__ dst,
                     const unsigned* __restrict__ rowptr, unsigned* __restrict__ cursor,
                     const float* __restrict__ nrm, int2* __restrict__ csrw)
{
    int gid = blockIdx.x * 256 + threadIdx.x;
    if (gid >= RE) return;
    int r = gid / Ee;
    int s = src[gid], d = dst[gid];
    int idx = r * Nn + d;
    unsigned pos = rowptr[idx] + atomicAdd(&cursor[idx], 1u);
    float w = nrm[r * Nn + s] * nrm[TOT + r * Nn + d];
    int2 v; v.x = s; v.y = __builtin_bit_cast(int, w);
    csrw[pos] = v;
}

__global__ void bsum_kernel(const float* __restrict__ b1, const float* __restrict__ b2,
                            float* __restrict__ bs1, float* __restrict__ bs2)
{
    int t = threadIdx.x;
    if (t < 128) bs1[t] = b1[t] + b1[128 + t] + b1[256 + t] + b1[384 + t];
    if (t < 64)  bs2[t] = b2[t] + b2[64 + t] + b2[128 + t] + b2[192 + t];
}

// ---------------- bf16 hi/lo conversions ----------------
__global__ __launch_bounds__(256)
void convw_kernel(const float* __restrict__ W1, const float* __restrict__ W2,
                  short* __restrict__ w1h, short* __restrict__ w1l,
                  short* __restrict__ w2h, short* __restrict__ w2l)
{
    int gid = blockIdx.x * 256 + threadIdx.x;
    if (gid < 4 * 128 * 128) {
        int r = gid >> 14, rem = gid & 16383, n = rem >> 7, k = rem & 127;
        float v = W1[(r << 14) + k * 128 + n];
        unsigned short h = f2bf(v);
        unsigned short l = f2bf(v - bf2f(h));
        w1h[(r << 14) + n * 128 + k] = (short)h;
        w1l[(r << 14) + n * 128 + k] = (short)l;
    } else {
        int g2 = gid - 65536;
        if (g2 >= 4 * 64 * 128) return;
        int r = g2 >> 13, rem = g2 & 8191, n = rem >> 7, k = rem & 127;
        float v = W2[(r << 13) + k * 64 + n];
        unsigned short h = f2bf(v);
        unsigned short l = f2bf(v - bf2f(h));
        w2h[(r << 13) + n * 128 + k] = (short)h;
        w2l[(r << 13) + n * 128 + k] = (short)l;
    }
}

// X[Nn][128] f32 -> Xh/Xl [NP][128] bf16 (pad rows zero)
__global__ __launch_bounds__(256)
void convx_kernel(const float* __restrict__ X, short* __restrict__ Xh,
                  short* __restrict__ Xl)
{
    size_t base = ((size_t)blockIdx.x * 256 + threadIdx.x) * 8;
    if (base >= (size_t)NP * 128) return;
    bf16x8 hv, lv;
    #pragma unroll
    for (int i = 0; i < 8; ++i) { hv[i] = 0; lv[i] = 0; }
    if (base < (size_t)Nn * 128) {
        float4 a = *reinterpret_cast<const float4*>(X + base);
        float4 b = *reinterpret_cast<const float4*>(X + base + 4);
        float f[8] = {a.x, a.y, a.z, a.w, b.x, b.y, b.z, b.w};
        #pragma unroll
        for (int i = 0; i < 8; ++i) {
            unsigned short h = f2bf(f[i]);
            hv[i] = (short)h;
            lv[i] = (short)f2bf(f[i] - bf2f(h));
        }
    }
    *reinterpret_cast<bf16x8*>(Xh + base) = hv;
    *reinterpret_cast<bf16x8*>(Xl + base) = lv;
}

// ---------------- MFMA GEMM: Y[:, rel*BN+...] = X @ W_rel (bf16 out) ----------------
template<int BN>
__global__ __launch_bounds__(256)
void gemm_kernel(const short* __restrict__ Xh, const short* __restrict__ Xl,
                 const short* __restrict__ WhT_, const short* __restrict__ WlT_,
                 short* __restrict__ Y_, int CW)
{
    constexpr int BM = 128, BKp = 40;            // 32 k + 8 pad (80B rows)
    constexpr int MFR = (BN == 128) ? 4 : 2;
    constexpr int NFR = 4;
    const short* WhT = WhT_ + (size_t)blockIdx.y * (BN * 128);
    const short* WlT = WlT_ + (size_t)blockIdx.y * (BN * 128);
    short* Y = Y_ + (size_t)blockIdx.y * BN;

    __shared__ __align__(16) short Ah[BM * BKp], Al[BM * BKp];
    __shared__ __align__(16) short Bh[BN * BKp], Bl[BN * BKp];

    const int tid = threadIdx.x;
    const int lane = tid & 63, wid = tid >> 6;
    const int lr = lane & 15, lg = lane >> 4;
    const int wm0 = (BN == 128) ? (wid >> 1) * 64 : wid * 32;
    const int wn0 = (BN == 128) ? (wid & 1) * 64 : 0;
    const int row0 = blockIdx.x * BM;

    f32x4 acc[MFR][NFR];
    #pragma unroll
    for (int m = 0; m < MFR; ++m)
        #pragma unroll
        for (int n = 0; n < NFR; ++n)
            #pragma unroll
            for (int j = 0; j < 4; ++j) acc[m][n][j] = 0.f;

    const int sr = tid >> 1;
    const int sko = (tid & 1) * 16;

    for (int ks = 0; ks < 4; ++ks) {
        size_t ga = (size_t)(row0 + sr) * 128 + ks * 32 + sko;
        *reinterpret_cast<bf16x8*>(&Ah[sr * BKp + sko])     = *reinterpret_cast<const bf16x8*>(&Xh[ga]);
        *reinterpret_cast<bf16x8*>(&Ah[sr * BKp + sko + 8]) = *reinterpret_cast<const bf16x8*>(&Xh[ga + 8]);
        *reinterpret_cast<bf16x8*>(&Al[sr * BKp + sko])     = *reinterpret_cast<const bf16x8*>(&Xl[ga]);
        *reinterpret_cast<bf16x8*>(&Al[sr * BKp + sko + 8]) = *reinterpret_cast<const bf16x8*>(&Xl[ga + 8]);
        if (BN == 128 || tid < 128) {
            size_t gb = (size_t)sr * 128 + ks * 32 + sko;
            *reinterpret_cast<bf16x8*>(&Bh[sr * BKp + sko])     = *reinterpret_cast<const bf16x8*>(&WhT[gb]);
            *reinterpret_cast<bf16x8*>(&Bh[sr * BKp + sko + 8]) = *reinterpret_cast<const bf16x8*>(&WhT[gb + 8]);
            *reinterpret_cast<bf16x8*>(&Bl[sr * BKp + sko])     = *reinterpret_cast<const bf16x8*>(&WlT[gb]);
            *reinterpret_cast<bf16x8*>(&Bl[sr * BKp + sko + 8]) = *reinterpret_cast<const bf16x8*>(&WlT[gb + 8]);
        }
        __syncthreads();

        bf16x8 bh[NFR], bl[NFR];
        #pragma unroll
        for (int n = 0; n < NFR; ++n) {
            bh[n] = *reinterpret_cast<const bf16x8*>(&Bh[(wn0 + n * 16 + lr) * BKp + lg * 8]);
            bl[n] = *reinterpret_cast<const bf16x8*>(&Bl[(wn0 + n * 16 + lr) * BKp + lg * 8]);
        }
        #pragma unroll
        for (int m = 0; m < MFR; ++m) {
            bf16x8 ah = *reinterpret_cast<const bf16x8*>(&Ah[(wm0 + m * 16 + lr) * BKp + lg * 8]);
            bf16x8 al = *reinterpret_cast<const bf16x8*>(&Al[(wm0 + m * 16 + lr) * BKp + lg * 8]);
            #pragma unroll
            for (int n = 0; n < NFR; ++n) {
                acc[m][n] = __builtin_amdgcn_mfma_f32_16x16x32_bf16(ah, bh[n], acc[m][n], 0, 0, 0);
                acc[m][n] = __builtin_amdgcn_mfma_f32_16x16x32_bf16(ah, bl[n], acc[m][n], 0, 0, 0);
                acc[m][n] = __builtin_amdgcn_mfma_f32_16x16x32_bf16(al, bh[n], acc[m][n], 0, 0, 0);
            }
        }
        __syncthreads();
    }

    // C/D layout: col=lane&15, row=(lane>>4)*4+j  [m89]
    #pragma unroll
    for (int m = 0; m < MFR; ++m)
        #pragma unroll
        for (int n = 0; n < NFR; ++n) {
            int col = wn0 + n * 16 + lr;
            int rb = row0 + wm0 + m * 16 + lg * 4;
            #pragma unroll
            for (int j = 0; j < 4; ++j)
                Y[(size_t)(rb + j) * CW + col] = (short)f2bf(acc[m][n][j]);
        }
}

// ---------------- CSR gather over NR relations (Y in bf16) ----------------
// F=128: optional finalize -> bias+sumH+ReLU+bf16 hi/lo split into Xh/Xl.
// F=64: writes f32 H (=out).
template<int F, int NR>
__global__ __launch_bounds__(256)
void gather_kernel(const short* __restrict__ Y, const unsigned* __restrict__ rowptr,
                   const int2* __restrict__ csrw, const float* __restrict__ bsum,
                   float* __restrict__ H, short* __restrict__ Xh, short* __restrict__ Xl,
                   int CW, int accumulate, int finalize)
{
    constexpr int VF = F / 64;
    int wid = (blockIdx.x * 256 + threadIdx.x) >> 6;
    int lane = threadIdx.x & 63;
    if (wid >= Nn) return;
    float t0 = 0.f, t1 = 0.f;
    #pragma unroll
    for (int rl = 0; rl < NR; ++rl) {
        const short* yr = Y + rl * F;
        unsigned e  = rowptr[rl * Nn + wid];
        unsigned e1 = rowptr[rl * Nn + wid + 1];
        for (; e + 2 <= e1; e += 2) {
            int2 a = csrw[e], b = csrw[e + 1];
            float wA = __builtin_bit_cast(float, a.y);
            float wB = __builtin_bit_cast(float, b.y);
            if constexpr (VF == 2) {
                unsigned pA = *reinterpret_cast<const unsigned*>(yr + (size_t)a.x * CW + lane * 2);
                unsigned pB = *reinterpret_cast<const unsigned*>(yr + (size_t)b.x * CW + lane * 2);
                t0 += wA * bfbits_lo(pA) + wB * bfbits_lo(pB);
                t1 += wA * bfbits_hi(pA) + wB * bfbits_hi(pB);
            } else {
                unsigned short vA = *reinterpret_cast<const unsigned short*>(yr + (size_t)a.x * CW + lane);
                unsigned short vB = *reinterpret_cast<const unsigned short*>(yr + (size_t)b.x * CW + lane);
                t0 += wA * bf2f(vA) + wB * bf2f(vB);
            }
        }
        if (e < e1) {
            int2 a = csrw[e];
            float wA = __builtin_bit_cast(float, a.y);
            if constexpr (VF == 2) {
                unsigned pA = *reinterpret_cast<const unsigned*>(yr + (size_t)a.x * CW + lane * 2);
                t0 += wA * bfbits_lo(pA);
                t1 += wA * bfbits_hi(pA);
            } else {
                unsigned short vA = *reinterpret_cast<const unsigned short*>(yr + (size_t)a.x * CW + lane);
                t0 += wA * bf2f(vA);
            }
        }
    }
    float* hp = H + (size_t)wid * F + lane * VF;
    if (accumulate) {
        t0 += hp[0]; if (VF == 2) t1 += hp[1];
    } else {
        t0 += bsum[lane * VF]; if (VF == 2) t1 += bsum[lane * VF + 1];
    }
    if (F == 128 && finalize) {
        // ReLU + bf16 hi/lo split straight into the next layer's input
        t0 = fmaxf(t0, 0.f); t1 = fmaxf(t1, 0.f);
        unsigned short h0 = f2bf(t0), h1 = f2bf(t1);
        short2 hv; hv.x = (short)h0; hv.y = (short)h1;
        short2 lv; lv.x = (short)f2bf(t0 - bf2f(h0)); lv.y = (short)f2bf(t1 - bf2f(h1));
        *reinterpret_cast<short2*>(Xh + (size_t)wid * F + lane * 2) = hv;
        *reinterpret_cast<short2*>(Xl + (size_t)wid * F + lane * 2) = lv;
    } else {
        if constexpr (VF == 2) *reinterpret_cast<float2*>(hp) = make_float2(t0, t1);
        else hp[0] = t0;
    }
}

extern "C" void kernel_launch(void* const* d_in, const int* in_sizes, int n_in,
                              void* d_out, int out_size, void* d_ws, size_t ws_size,
                              hipStream_t stream)
{
    const float* x  = (const float*)d_in[0];
    const int* esrc = (const int*)d_in[1];
    const int* edst = (const int*)d_in[2];
    const float* W1 = (const float*)d_in[3];
    const float* b1 = (const float*)d_in[4];
    const float* W2 = (const float*)d_in[5];
    const float* b2 = (const float*)d_in[6];
    float* out = (float*)d_out;

    // ---- workspace layout ----
    char* ws = (char*)d_ws;
    size_t off = 0;
    auto alloc = [&](size_t bytes) { char* p = ws + off; off += (bytes + 255) & ~(size_t)255; return p; };
    unsigned* degS    = (unsigned*)alloc((size_t)2 * SH * TOT * 4);   // 12.8MB
    unsigned* dsum    = (unsigned*)alloc((size_t)TOT * 4);
    float*    nrm     = (float*)   alloc((size_t)2 * TOT * 4);
    unsigned* rowptr  = (unsigned*)alloc((size_t)(TOT + 1) * 4);
    unsigned* cursor  = (unsigned*)alloc((size_t)TOT * 4);
    unsigned* partial = (unsigned*)alloc((size_t)NB1 * 4);
    float*    bs1     = (float*)   alloc(128 * 4);
    float*    bs2     = (float*)   alloc(64 * 4);
    short*    w1h     = (short*)   alloc((size_t)4 * 128 * 128 * 2);
    short*    w1l     = (short*)   alloc((size_t)4 * 128 * 128 * 2);
    short*    w2h     = (short*)   alloc((size_t)4 * 64 * 128 * 2);
    short*    w2l     = (short*)   alloc((size_t)4 * 64 * 128 * 2);
    int2*     csrw    = (int2*)    alloc((size_t)RE * 8);             // 16MB
    short*    xh      = (short*)   alloc((size_t)NP * 128 * 2);
    short*    xl      = (short*)   alloc((size_t)NP * 128 * 2);

    size_t yslot = (size_t)NP * 128 * 2;          // 25.6MB (bf16, 128 cols)
    bool pathA = (ws_size >= off + 4 * yslot + 4096);
    float* h = nullptr;
    short* Y;
    if (pathA) {
        Y = (short*)alloc(4 * yslot);             // 4 relations side by side
    } else {
        h = (float*)alloc((size_t)NP * 128 * 4);  // f32 partial accumulator
        Y = (short*)alloc(yslot);                 // 1 relation at a time
    }

    // ---- preprocessing ----
    hipMemsetAsync(degS, 0, (size_t)2 * SH * TOT * 4, stream);
    hipMemsetAsync(cursor, 0, (size_t)TOT * 4, stream);
    count_deg_kernel<<<(RE + 255) / 256, 256, 0, stream>>>(esrc, edst, degS);
    norms_kernel<<<(TOT + 255) / 256, 256, 0, stream>>>(degS, nrm, dsum);
    scan1_kernel<<<NB1, 256, 0, stream>>>(dsum, partial);
    scan2_kernel<<<1, NB1, 0, stream>>>(partial, rowptr);
    scan3_kernel<<<NB1, 256, 0, stream>>>(dsum, partial, rowptr);
    fill_csr_kernel<<<(RE + 255) / 256, 256, 0, stream>>>(esrc, edst, rowptr, cursor, nrm, csrw);
    bsum_kernel<<<1, 128, 0, stream>>>(b1, b2, bs1, bs2);
    convw_kernel<<<384, 256, 0, stream>>>(W1, W2, w1h, w1l, w2h, w2l);
    convx_kernel<<<(NP * 128 / 8 + 255) / 256, 256, 0, stream>>>(x, xh, xl);

    const int ggrid = (Nn * 64 + 255) / 256;      // one wave per dst node

    if (pathA) {
        // ---- layer 1: all 4 relations in one GEMM + one gather ----
        gemm_kernel<128><<<dim3(NPB, 4), 256, 0, stream>>>(xh, xl, w1h, w1l, Y, 512);
        gather_kernel<128, 4><<<ggrid, 256, 0, stream>>>(
            Y, rowptr, csrw, bs1, out /*unused*/, xh, xl, 512, 0, 1);
        // ---- layer 2 ----
        gemm_kernel<64><<<dim3(NPB, 4), 256, 0, stream>>>(xh, xl, w2h, w2l, Y, 256);
        gather_kernel<64, 4><<<ggrid, 256, 0, stream>>>(
            Y, rowptr, csrw, bs2, out, nullptr, nullptr, 256, 0, 0);
    } else {
        // ---- layer 1, per relation; last pass fuses ReLU+split into xh/xl ----
        for (int r = 0; r < Rr; ++r) {
            gemm_kernel<128><<<dim3(NPB, 1), 256, 0, stream>>>(
                xh, xl, w1h + (size_t)r * 128 * 128, w1l + (size_t)r * 128 * 128, Y, 128);
            gather_kernel<128, 1><<<ggrid, 256, 0, stream>>>(
                Y, rowptr + (size_t)r * Nn, csrw, bs1, h, xh, xl, 128, r > 0, r == Rr - 1);
        }
        // ---- layer 2 ----
        for (int r = 0; r < Rr; ++r) {
            gemm_kernel<64><<<dim3(NPB, 1), 256, 0, stream>>>(
                xh, xl, w2h + (size_t)r * 64 * 128, w2l + (size_t)r * 64 * 128, Y, 64);
            gather_kernel<64, 1><<<ggrid, 256, 0, stream>>>(
                Y, rowptr + (size_t)r * Nn, csrw, bs2, out, nullptr, nullptr, 64, r > 0, 0);
        }
    }
}

// Round 5
// 644.494 us; speedup vs baseline: 8.9409x; 1.0684x over previous
//
#include <hip/hip_runtime.h>

// RGCN: 2-layer, R=4, N=100000, E=500000/rel, 128->128->64.
// Round 5: dst-atomic returns CSR slot (atomic-free fill); batched count;
// packed {rowptr,ndst}; 4-edge-unrolled gather; bf16 Y; fused layer pipeline.

constexpr int Nn  = 100000;
constexpr int Rr  = 4;
constexpr int Ee  = 500000;
constexpr int RE  = Rr * Ee;
constexpr int TOT = Rr * Nn;
constexpr int NP  = 100096;            // Nn padded to 128 rows
constexpr int NPB = NP / 128;          // 782 row-blocks
constexpr int NB1 = 1024;
constexpr int CH  = (TOT + NB1 - 1) / NB1;

typedef short bf16x8 __attribute__((ext_vector_type(8)));
typedef float f32x4  __attribute__((ext_vector_type(4)));

__device__ __forceinline__ unsigned short f2bf(float f) {
    unsigned u = __builtin_bit_cast(unsigned, f);
    u = u + 0x7FFFu + ((u >> 16) & 1u);          // round-to-nearest-even
    return (unsigned short)(u >> 16);
}
__device__ __forceinline__ float bf2f(unsigned short h) {
    unsigned u = ((unsigned)h) << 16;
    return __builtin_bit_cast(float, u);
}
__device__ __forceinline__ float bfbits_lo(unsigned p) {
    return __builtin_bit_cast(float, p << 16);
}
__device__ __forceinline__ float bfbits_hi(unsigned p) {
    return __builtin_bit_cast(float, p & 0xFFFF0000u);
}

// ---------------- graph preprocessing ----------------
// deg: [2][TOT] u32  (side 0 = src/out-degree, side 1 = dst/in-degree)
// slot[e] = rank of edge e within its (r,dst) segment (from the dst atomic).
__global__ __launch_bounds__(256)
void count_deg_kernel(const int* __restrict__ src, const int* __restrict__ dst,
                      unsigned* __restrict__ deg, unsigned* __restrict__ slot)
{
    int e0 = (blockIdx.x * 256 + threadIdx.x) * 4;
    if (e0 >= RE) return;
    int r = e0 / Ee;                    // Ee%4==0 -> batch within one relation
    int base = r * Nn;
    int4 s4 = *reinterpret_cast<const int4*>(src + e0);
    int4 d4 = *reinterpret_cast<const int4*>(dst + e0);
    atomicAdd(&deg[base + s4.x], 1u);
    atomicAdd(&deg[base + s4.y], 1u);
    atomicAdd(&deg[base + s4.z], 1u);
    atomicAdd(&deg[base + s4.w], 1u);
    uint4 sl;
    sl.x = atomicAdd(&deg[TOT + base + d4.x], 1u);
    sl.y = atomicAdd(&deg[TOT + base + d4.y], 1u);
    sl.z = atomicAdd(&deg[TOT + base + d4.z], 1u);
    sl.w = atomicAdd(&deg[TOT + base + d4.w], 1u);
    *reinterpret_cast<uint4*>(slot + e0) = sl;
}

// norms for both sides; stash ndst bits into the packed rpnd array
__global__ __launch_bounds__(256)
void norms_kernel(const unsigned* __restrict__ deg, float* __restrict__ nrm,
                  uint2* __restrict__ rpnd)
{
    int gid = blockIdx.x * 256 + threadIdx.x;
    if (gid >= TOT) return;
    unsigned s = deg[gid], d = deg[TOT + gid];
    float ns = rsqrtf((float)(s > 0u ? s : 1u));
    float nd = rsqrtf((float)(d > 0u ? d : 1u));
    nrm[gid] = ns;
    rpnd[gid].y = __builtin_bit_cast(unsigned, nd);
}

__global__ __launch_bounds__(256)
void scan1_kernel(const unsigned* __restrict__ deg, unsigned* __restrict__ partial)
{
    __shared__ unsigned s[256];
    int b = blockIdx.x, t = threadIdx.x;
    int start = b * CH;
    int n = TOT - start; if (n > CH) n = CH;
    unsigned sum = 0;
    for (int i = t; i < n; i += 256) sum += deg[TOT + start + i];
    s[t] = sum; __syncthreads();
    for (int d = 128; d > 0; d >>= 1) {
        if (t < d) s[t] += s[t + d];
        __syncthreads();
    }
    if (t == 0) partial[b] = s[0];
}

__global__ __launch_bounds__(1024)
void scan2_kernel(unsigned* __restrict__ partial, unsigned* __restrict__ rowptr)
{
    __shared__ unsigned s[NB1];
    int t = threadIdx.x;
    unsigned orig = partial[t];
    s[t] = orig; __syncthreads();
    for (int d = 1; d < NB1; d <<= 1) {
        unsigned v = (t >= d) ? s[t - d] : 0u;
        __syncthreads();
        s[t] += v;
        __syncthreads();
    }
    partial[t] = s[t] - orig;
    if (t == 0) rowptr[TOT] = (unsigned)RE;
}

__global__ __launch_bounds__(256)
void scan3_kernel(const unsigned* __restrict__ deg, const unsigned* __restrict__ base,
                  unsigned* __restrict__ rowptr, uint2* __restrict__ rpnd)
{
    __shared__ unsigned s[CH];
    int b = blockIdx.x, t = threadIdx.x;
    int start = b * CH;
    int n = TOT - start; if (n > CH) n = CH;
    if (n <= 0) return;
    for (int i = t; i < n; i += 256) s[i] = deg[TOT + start + i];
    __syncthreads();
    if (t == 0) {
        unsigned run = base[b];
        for (int i = 0; i < n; ++i) { unsigned v = s[i]; s[i] = run; run += v; }
    }
    __syncthreads();
    for (int i = t; i < n; i += 256) {
        unsigned v = s[i];
        rowptr[start + i] = v;
        rpnd[start + i].x = v;
    }
}

// atomic-free CSR fill: pos = rowptr + slot
__global__ __launch_bounds__(256)
void fill_csr_kernel(const int* __restrict__ src, const int* __restrict__ dst,
                     const unsigned* __restrict__ slot, const uint2* __restrict__ rpnd,
                     const float* __restrict__ nrm, int2* __restrict__ csrw)
{
    int e0 = (blockIdx.x * 256 + threadIdx.x) * 4;
    if (e0 >= RE) return;
    int r = e0 / Ee;
    int base = r * Nn;
    int4 s4 = *reinterpret_cast<const int4*>(src + e0);
    int4 d4 = *reinterpret_cast<const int4*>(dst + e0);
    uint4 sl = *reinterpret_cast<const uint4*>(slot + e0);
    #pragma unroll
    for (int i = 0; i < 4; ++i) {
        int s = (i == 0) ? s4.x : (i == 1) ? s4.y : (i == 2) ? s4.z : s4.w;
        int d = (i == 0) ? d4.x : (i == 1) ? d4.y : (i == 2) ? d4.z : d4.w;
        unsigned k = (i == 0) ? sl.x : (i == 1) ? sl.y : (i == 2) ? sl.z : sl.w;
        uint2 rn = rpnd[base + d];
        float w = nrm[base + s] * __builtin_bit_cast(float, rn.y);
        int2 v; v.x = s; v.y = __builtin_bit_cast(int, w);
        csrw[rn.x + k] = v;
    }
}

__global__ void bsum_kernel(const float* __restrict__ b1, const float* __restrict__ b2,
                            float* __restrict__ bs1, float* __restrict__ bs2)
{
    int t = threadIdx.x;
    if (t < 128) bs1[t] = b1[t] + b1[128 + t] + b1[256 + t] + b1[384 + t];
    if (t < 64)  bs2[t] = b2[t] + b2[64 + t] + b2[128 + t] + b2[192 + t];
}

// ---------------- bf16 hi/lo conversions ----------------
__global__ __launch_bounds__(256)
void convw_kernel(const float* __restrict__ W1, const float* __restrict__ W2,
                  short* __restrict__ w1h, short* __restrict__ w1l,
                  short* __restrict__ w2h, short* __restrict__ w2l)
{
    int gid = blockIdx.x * 256 + threadIdx.x;
    if (gid < 4 * 128 * 128) {
        int r = gid >> 14, rem = gid & 16383, n = rem >> 7, k = rem & 127;
        float v = W1[(r << 14) + k * 128 + n];
        unsigned short h = f2bf(v);
        unsigned short l = f2bf(v - bf2f(h));
        w1h[(r << 14) + n * 128 + k] = (short)h;
        w1l[(r << 14) + n * 128 + k] = (short)l;
    } else {
        int g2 = gid - 65536;
        if (g2 >= 4 * 64 * 128) return;
        int r = g2 >> 13, rem = g2 & 8191, n = rem >> 7, k = rem & 127;
        float v = W2[(r << 13) + k * 64 + n];
        unsigned short h = f2bf(v);
        unsigned short l = f2bf(v - bf2f(h));
        w2h[(r << 13) + n * 128 + k] = (short)h;
        w2l[(r << 13) + n * 128 + k] = (short)l;
    }
}

__global__ __launch_bounds__(256)
void convx_kernel(const float* __restrict__ X, short* __restrict__ Xh,
                  short* __restrict__ Xl)
{
    size_t base = ((size_t)blockIdx.x * 256 + threadIdx.x) * 8;
    if (base >= (size_t)NP * 128) return;
    bf16x8 hv, lv;
    #pragma unroll
    for (int i = 0; i < 8; ++i) { hv[i] = 0; lv[i] = 0; }
    if (base < (size_t)Nn * 128) {
        float4 a = *reinterpret_cast<const float4*>(X + base);
        float4 b = *reinterpret_cast<const float4*>(X + base + 4);
        float f[8] = {a.x, a.y, a.z, a.w, b.x, b.y, b.z, b.w};
        #pragma unroll
        for (int i = 0; i < 8; ++i) {
            unsigned short h = f2bf(f[i]);
            hv[i] = (short)h;
            lv[i] = (short)f2bf(f[i] - bf2f(h));
        }
    }
    *reinterpret_cast<bf16x8*>(Xh + base) = hv;
    *reinterpret_cast<bf16x8*>(Xl + base) = lv;
}

// ---------------- MFMA GEMM: Y[:, rel*BN+...] = X @ W_rel (bf16 out) ----------------
template<int BN>
__global__ __launch_bounds__(256)
void gemm_kernel(const short* __restrict__ Xh, const short* __restrict__ Xl,
                 const short* __restrict__ WhT_, const short* __restrict__ WlT_,
                 short* __restrict__ Y_, int CW)
{
    constexpr int BM = 128, BKp = 40;            // 32 k + 8 pad
    constexpr int MFR = (BN == 128) ? 4 : 2;
    constexpr int NFR = 4;
    const short* WhT = WhT_ + (size_t)blockIdx.y * (BN * 128);
    const short* WlT = WlT_ + (size_t)blockIdx.y * (BN * 128);
    short* Y = Y_ + (size_t)blockIdx.y * BN;

    __shared__ __align__(16) short Ah[BM * BKp], Al[BM * BKp];
    __shared__ __align__(16) short Bh[BN * BKp], Bl[BN * BKp];

    const int tid = threadIdx.x;
    const int lane = tid & 63, wid = tid >> 6;
    const int lr = lane & 15, lg = lane >> 4;
    const int wm0 = (BN == 128) ? (wid >> 1) * 64 : wid * 32;
    const int wn0 = (BN == 128) ? (wid & 1) * 64 : 0;
    const int row0 = blockIdx.x * BM;

    f32x4 acc[MFR][NFR];
    #pragma unroll
    for (int m = 0; m < MFR; ++m)
        #pragma unroll
        for (int n = 0; n < NFR; ++n)
            #pragma unroll
            for (int j = 0; j < 4; ++j) acc[m][n][j] = 0.f;

    const int sr = tid >> 1;
    const int sko = (tid & 1) * 16;

    for (int ks = 0; ks < 4; ++ks) {
        size_t ga = (size_t)(row0 + sr) * 128 + ks * 32 + sko;
        *reinterpret_cast<bf16x8*>(&Ah[sr * BKp + sko])     = *reinterpret_cast<const bf16x8*>(&Xh[ga]);
        *reinterpret_cast<bf16x8*>(&Ah[sr * BKp + sko + 8]) = *reinterpret_cast<const bf16x8*>(&Xh[ga + 8]);
        *reinterpret_cast<bf16x8*>(&Al[sr * BKp + sko])     = *reinterpret_cast<const bf16x8*>(&Xl[ga]);
        *reinterpret_cast<bf16x8*>(&Al[sr * BKp + sko + 8]) = *reinterpret_cast<const bf16x8*>(&Xl[ga + 8]);
        if (BN == 128 || tid < 128) {
            size_t gb = (size_t)sr * 128 + ks * 32 + sko;
            *reinterpret_cast<bf16x8*>(&Bh[sr * BKp + sko])     = *reinterpret_cast<const bf16x8*>(&WhT[gb]);
            *reinterpret_cast<bf16x8*>(&Bh[sr * BKp + sko + 8]) = *reinterpret_cast<const bf16x8*>(&WhT[gb + 8]);
            *reinterpret_cast<bf16x8*>(&Bl[sr * BKp + sko])     = *reinterpret_cast<const bf16x8*>(&WlT[gb]);
            *reinterpret_cast<bf16x8*>(&Bl[sr * BKp + sko + 8]) = *reinterpret_cast<const bf16x8*>(&WlT[gb + 8]);
        }
        __syncthreads();

        bf16x8 bh[NFR], bl[NFR];
        #pragma unroll
        for (int n = 0; n < NFR; ++n) {
            bh[n] = *reinterpret_cast<const bf16x8*>(&Bh[(wn0 + n * 16 + lr) * BKp + lg * 8]);
            bl[n] = *reinterpret_cast<const bf16x8*>(&Bl[(wn0 + n * 16 + lr) * BKp + lg * 8]);
        }
        #pragma unroll
        for (int m = 0; m < MFR; ++m) {
            bf16x8 ah = *reinterpret_cast<const bf16x8*>(&Ah[(wm0 + m * 16 + lr) * BKp + lg * 8]);
            bf16x8 al = *reinterpret_cast<const bf16x8*>(&Al[(wm0 + m * 16 + lr) * BKp + lg * 8]);
            #pragma unroll
            for (int n = 0; n < NFR; ++n) {
                acc[m][n] = __builtin_amdgcn_mfma_f32_16x16x32_bf16(ah, bh[n], acc[m][n], 0, 0, 0);
                acc[m][n] = __builtin_amdgcn_mfma_f32_16x16x32_bf16(ah, bl[n], acc[m][n], 0, 0, 0);
                acc[m][n] = __builtin_amdgcn_mfma_f32_16x16x32_bf16(al, bh[n], acc[m][n], 0, 0, 0);
            }
        }
        __syncthreads();
    }

    // C/D layout: col=lane&15, row=(lane>>4)*4+j  [m89]
    #pragma unroll
    for (int m = 0; m < MFR; ++m)
        #pragma unroll
        for (int n = 0; n < NFR; ++n) {
            int col = wn0 + n * 16 + lr;
            int rb = row0 + wm0 + m * 16 + lg * 4;
            #pragma unroll
            for (int j = 0; j < 4; ++j)
                Y[(size_t)(rb + j) * CW + col] = (short)f2bf(acc[m][n][j]);
        }
}

// ---------------- CSR gather over NR relations (Y bf16), 4-edge unrolled ----------------
template<int F, int NR>
__global__ __launch_bounds__(256)
void gather_kernel(const short* __restrict__ Y, const unsigned* __restrict__ rowptr,
                   const int2* __restrict__ csrw, const float* __restrict__ bsum,
                   float* __restrict__ H, short* __restrict__ Xh, short* __restrict__ Xl,
                   int CW, int accumulate, int finalize)
{
    constexpr int VF = F / 64;
    int wid = (blockIdx.x * 256 + threadIdx.x) >> 6;
    int lane = threadIdx.x & 63;
    if (wid >= Nn) return;
    float t0 = 0.f, t1 = 0.f;
    #pragma unroll
    for (int rl = 0; rl < NR; ++rl) {
        const short* yr = Y + rl * F;
        unsigned e  = rowptr[rl * Nn + wid];
        unsigned e1 = rowptr[rl * Nn + wid + 1];
        for (; e + 4 <= e1; e += 4) {
            int2 a0 = csrw[e], a1 = csrw[e + 1], a2 = csrw[e + 2], a3 = csrw[e + 3];
            float w0 = __builtin_bit_cast(float, a0.y);
            float w1 = __builtin_bit_cast(float, a1.y);
            float w2 = __builtin_bit_cast(float, a2.y);
            float w3 = __builtin_bit_cast(float, a3.y);
            if constexpr (VF == 2) {
                unsigned p0 = *reinterpret_cast<const unsigned*>(yr + (size_t)a0.x * CW + lane * 2);
                unsigned p1 = *reinterpret_cast<const unsigned*>(yr + (size_t)a1.x * CW + lane * 2);
                unsigned p2 = *reinterpret_cast<const unsigned*>(yr + (size_t)a2.x * CW + lane * 2);
                unsigned p3 = *reinterpret_cast<const unsigned*>(yr + (size_t)a3.x * CW + lane * 2);
                t0 += w0 * bfbits_lo(p0) + w1 * bfbits_lo(p1) + w2 * bfbits_lo(p2) + w3 * bfbits_lo(p3);
                t1 += w0 * bfbits_hi(p0) + w1 * bfbits_hi(p1) + w2 * bfbits_hi(p2) + w3 * bfbits_hi(p3);
            } else {
                unsigned short v0 = *reinterpret_cast<const unsigned short*>(yr + (size_t)a0.x * CW + lane);
                unsigned short v1 = *reinterpret_cast<const unsigned short*>(yr + (size_t)a1.x * CW + lane);
                unsigned short v2 = *reinterpret_cast<const unsigned short*>(yr + (size_t)a2.x * CW + lane);
                unsigned short v3 = *reinterpret_cast<const unsigned short*>(yr + (size_t)a3.x * CW + lane);
                t0 += w0 * bf2f(v0) + w1 * bf2f(v1) + w2 * bf2f(v2) + w3 * bf2f(v3);
            }
        }
        for (; e < e1; ++e) {
            int2 a = csrw[e];
            float wA = __builtin_bit_cast(float, a.y);
            if constexpr (VF == 2) {
                unsigned pA = *reinterpret_cast<const unsigned*>(yr + (size_t)a.x * CW + lane * 2);
                t0 += wA * bfbits_lo(pA);
                t1 += wA * bfbits_hi(pA);
            } else {
                unsigned short vA = *reinterpret_cast<const unsigned short*>(yr + (size_t)a.x * CW + lane);
                t0 += wA * bf2f(vA);
            }
        }
    }
    float* hp = H + (size_t)wid * F + lane * VF;
    if (accumulate) {
        t0 += hp[0]; if (VF == 2) t1 += hp[1];
    } else {
        t0 += bsum[lane * VF]; if (VF == 2) t1 += bsum[lane * VF + 1];
    }
    if (F == 128 && finalize) {
        t0 = fmaxf(t0, 0.f); t1 = fmaxf(t1, 0.f);
        unsigned short h0 = f2bf(t0), h1 = f2bf(t1);
        short2 hv; hv.x = (short)h0; hv.y = (short)h1;
        short2 lv; lv.x = (short)f2bf(t0 - bf2f(h0)); lv.y = (short)f2bf(t1 - bf2f(h1));
        *reinterpret_cast<short2*>(Xh + (size_t)wid * F + lane * 2) = hv;
        *reinterpret_cast<short2*>(Xl + (size_t)wid * F + lane * 2) = lv;
    } else {
        if constexpr (VF == 2) *reinterpret_cast<float2*>(hp) = make_float2(t0, t1);
        else hp[0] = t0;
    }
}

extern "C" void kernel_launch(void* const* d_in, const int* in_sizes, int n_in,
                              void* d_out, int out_size, void* d_ws, size_t ws_size,
                              hipStream_t stream)
{
    const float* x  = (const float*)d_in[0];
    const int* esrc = (const int*)d_in[1];
    const int* edst = (const int*)d_in[2];
    const float* W1 = (const float*)d_in[3];
    const float* b1 = (const float*)d_in[4];
    const float* W2 = (const float*)d_in[5];
    const float* b2 = (const float*)d_in[6];
    float* out = (float*)d_out;

    // ---- workspace layout ----
    char* ws = (char*)d_ws;
    size_t off = 0;
    auto alloc = [&](size_t bytes) { char* p = ws + off; off += (bytes + 255) & ~(size_t)255; return p; };
    unsigned* deg     = (unsigned*)alloc((size_t)2 * TOT * 4);      // 3.2MB
    float*    nrm     = (float*)   alloc((size_t)TOT * 4);          // nsrc only
    uint2*    rpnd    = (uint2*)   alloc((size_t)TOT * 8);          // {rowptr, ndst}
    unsigned* rowptr  = (unsigned*)alloc((size_t)(TOT + 1) * 4);
    unsigned* partial = (unsigned*)alloc((size_t)NB1 * 4);
    unsigned* slot    = (unsigned*)alloc((size_t)RE * 4);           // 8MB
    float*    bs1     = (float*)   alloc(128 * 4);
    float*    bs2     = (float*)   alloc(64 * 4);
    short*    w1h     = (short*)   alloc((size_t)4 * 128 * 128 * 2);
    short*    w1l     = (short*)   alloc((size_t)4 * 128 * 128 * 2);
    short*    w2h     = (short*)   alloc((size_t)4 * 64 * 128 * 2);
    short*    w2l     = (short*)   alloc((size_t)4 * 64 * 128 * 2);
    int2*     csrw    = (int2*)    alloc((size_t)RE * 8);           // 16MB
    short*    xh      = (short*)   alloc((size_t)NP * 128 * 2);
    short*    xl      = (short*)   alloc((size_t)NP * 128 * 2);

    size_t yslot = (size_t)NP * 128 * 2;          // 25.6MB (bf16, 128 cols)
    bool pathA = (ws_size >= off + 4 * yslot + 4096);
    float* h = nullptr;
    short* Y;
    if (pathA) {
        Y = (short*)alloc(4 * yslot);
    } else {
        h = (float*)alloc((size_t)NP * 128 * 4);
        Y = (short*)alloc(yslot);
    }

    // ---- preprocessing ----
    hipMemsetAsync(deg, 0, (size_t)2 * TOT * 4, stream);
    count_deg_kernel<<<(RE / 4 + 255) / 256, 256, 0, stream>>>(esrc, edst, deg, slot);
    norms_kernel<<<(TOT + 255) / 256, 256, 0, stream>>>(deg, nrm, rpnd);
    scan1_kernel<<<NB1, 256, 0, stream>>>(deg, partial);
    scan2_kernel<<<1, NB1, 0, stream>>>(partial, rowptr);
    scan3_kernel<<<NB1, 256, 0, stream>>>(deg, partial, rowptr, rpnd);
    fill_csr_kernel<<<(RE / 4 + 255) / 256, 256, 0, stream>>>(esrc, edst, slot, rpnd, nrm, csrw);
    bsum_kernel<<<1, 128, 0, stream>>>(b1, b2, bs1, bs2);
    convw_kernel<<<384, 256, 0, stream>>>(W1, W2, w1h, w1l, w2h, w2l);
    convx_kernel<<<(NP * 128 / 8 + 255) / 256, 256, 0, stream>>>(x, xh, xl);

    const int ggrid = (Nn * 64 + 255) / 256;      // one wave per dst node

    if (pathA) {
        gemm_kernel<128><<<dim3(NPB, 4), 256, 0, stream>>>(xh, xl, w1h, w1l, Y, 512);
        gather_kernel<128, 4><<<ggrid, 256, 0, stream>>>(
            Y, rowptr, csrw, bs1, out /*unused*/, xh, xl, 512, 0, 1);
        gemm_kernel<64><<<dim3(NPB, 4), 256, 0, stream>>>(xh, xl, w2h, w2l, Y, 256);
        gather_kernel<64, 4><<<ggrid, 256, 0, stream>>>(
            Y, rowptr, csrw, bs2, out, nullptr, nullptr, 256, 0, 0);
    } else {
        for (int r = 0; r < Rr; ++r) {
            gemm_kernel<128><<<dim3(NPB, 1), 256, 0, stream>>>(
                xh, xl, w1h + (size_t)r * 128 * 128, w1l + (size_t)r * 128 * 128, Y, 128);
            gather_kernel<128, 1><<<ggrid, 256, 0, stream>>>(
                Y, rowptr + (size_t)r * Nn, csrw, bs1, h, xh, xl, 128, r > 0, r == Rr - 1);
        }
        for (int r = 0; r < Rr; ++r) {
            gemm_kernel<64><<<dim3(NPB, 1), 256, 0, stream>>>(
                xh, xl, w2h + (size_t)r * 64 * 128, w2l + (size_t)r * 64 * 128, Y, 64);
            gather_kernel<64, 1><<<ggrid, 256, 0, stream>>>(
                Y, rowptr + (size_t)r * Nn, csrw, bs2, out, nullptr, nullptr, 64, r > 0, 0);
        }
    }
}

// Round 6
// 605.182 us; speedup vs baseline: 9.5216x; 1.0650x over previous
//
#include <hip/hip_runtime.h>

// RGCN: 2-layer, R=4, N=100000, E=500000/rel, 128->128->64.
// Round 6: 1-edge/thread count with slot-returning dst atomic; grid-fused
// prep (count || convx || convw || bsum) and (fill_csr || gemm128);
// bf16 Y; MFMA bf16-split GEMM; CSR gather.

constexpr int Nn  = 100000;
constexpr int Rr  = 4;
constexpr int Ee  = 500000;
constexpr int RE  = Rr * Ee;
constexpr int TOT = Rr * Nn;
constexpr int NP  = 100096;            // Nn padded to 128 rows
constexpr int NPB = NP / 128;          // 782 row-blocks
constexpr int NB1 = 1024;
constexpr int CH  = (TOT + NB1 - 1) / NB1;

// fused-prep grid decode
constexpr int CB   = (RE + 255) / 256;              // 7813 count blocks
constexpr int XB   = (NP * 128 / 8 + 255) / 256;    // 6256 convx blocks
constexpr int WB   = 384;                           // convw blocks (exact)
constexpr int PAIR = 2 * XB;                        // interleaved region
constexpr int PREP_GRID = PAIR + (CB - XB) + WB + 1;

// fused fill+gemm grid decode
constexpr int FB    = (RE / 4 + 255) / 256;         // 1954 fill blocks
constexpr int GB    = 4 * NPB;                      // 3128 gemm blocks
constexpr int PAIR2 = 2 * FB;
constexpr int FG_GRID = PAIR2 + (GB - FB);

typedef short bf16x8 __attribute__((ext_vector_type(8)));
typedef float f32x4  __attribute__((ext_vector_type(4)));

__device__ __forceinline__ unsigned short f2bf(float f) {
    unsigned u = __builtin_bit_cast(unsigned, f);
    u = u + 0x7FFFu + ((u >> 16) & 1u);          // round-to-nearest-even
    return (unsigned short)(u >> 16);
}
__device__ __forceinline__ float bf2f(unsigned short h) {
    unsigned u = ((unsigned)h) << 16;
    return __builtin_bit_cast(float, u);
}
__device__ __forceinline__ float bfbits_lo(unsigned p) {
    return __builtin_bit_cast(float, p << 16);
}
__device__ __forceinline__ float bfbits_hi(unsigned p) {
    return __builtin_bit_cast(float, p & 0xFFFF0000u);
}

// ---------------- role bodies ----------------
__device__ __forceinline__ void count_body(int sub, int tid,
    const int* __restrict__ src, const int* __restrict__ dst,
    unsigned* __restrict__ deg, unsigned* __restrict__ slot)
{
    int e = sub * 256 + tid;
    if (e >= RE) return;
    int r = (unsigned)e / (unsigned)Ee;
    int base = r * Nn;
    atomicAdd(&deg[base + src[e]], 1u);                     // fire-and-forget
    slot[e] = atomicAdd(&deg[TOT + base + dst[e]], 1u);     // rank in segment
}

__device__ __forceinline__ void convx_body(int sub, int tid,
    const float* __restrict__ X, short* __restrict__ Xh, short* __restrict__ Xl)
{
    size_t base = ((size_t)sub * 256 + tid) * 8;
    if (base >= (size_t)NP * 128) return;
    bf16x8 hv, lv;
    #pragma unroll
    for (int i = 0; i < 8; ++i) { hv[i] = 0; lv[i] = 0; }
    if (base < (size_t)Nn * 128) {
        float4 a = *reinterpret_cast<const float4*>(X + base);
        float4 b = *reinterpret_cast<const float4*>(X + base + 4);
        float f[8] = {a.x, a.y, a.z, a.w, b.x, b.y, b.z, b.w};
        #pragma unroll
        for (int i = 0; i < 8; ++i) {
            unsigned short h = f2bf(f[i]);
            hv[i] = (short)h;
            lv[i] = (short)f2bf(f[i] - bf2f(h));
        }
    }
    *reinterpret_cast<bf16x8*>(Xh + base) = hv;
    *reinterpret_cast<bf16x8*>(Xl + base) = lv;
}

__device__ __forceinline__ void convw_body(int sub, int tid,
    const float* __restrict__ W1, const float* __restrict__ W2,
    short* __restrict__ w1h, short* __restrict__ w1l,
    short* __restrict__ w2h, short* __restrict__ w2l)
{
    int gid = sub * 256 + tid;
    if (gid < 4 * 128 * 128) {
        int r = gid >> 14, rem = gid & 16383, n = rem >> 7, k = rem & 127;
        float v = W1[(r << 14) + k * 128 + n];
        unsigned short h = f2bf(v);
        unsigned short l = f2bf(v - bf2f(h));
        w1h[(r << 14) + n * 128 + k] = (short)h;
        w1l[(r << 14) + n * 128 + k] = (short)l;
    } else {
        int g2 = gid - 65536;
        if (g2 >= 4 * 64 * 128) return;
        int r = g2 >> 13, rem = g2 & 8191, n = rem >> 7, k = rem & 127;
        float v = W2[(r << 13) + k * 64 + n];
        unsigned short h = f2bf(v);
        unsigned short l = f2bf(v - bf2f(h));
        w2h[(r << 13) + n * 128 + k] = (short)h;
        w2l[(r << 13) + n * 128 + k] = (short)l;
    }
}

__device__ __forceinline__ void bsum_body(int tid,
    const float* __restrict__ b1, const float* __restrict__ b2,
    float* __restrict__ bs1, float* __restrict__ bs2)
{
    if (tid < 128) bs1[tid] = b1[tid] + b1[128 + tid] + b1[256 + tid] + b1[384 + tid];
    if (tid < 64)  bs2[tid] = b2[tid] + b2[64 + tid] + b2[128 + tid] + b2[192 + tid];
}

// ---------------- fused prep: count || convx || convw || bsum ----------------
__global__ __launch_bounds__(256)
void prep_kernel(const int* __restrict__ src, const int* __restrict__ dst,
                 unsigned* __restrict__ deg, unsigned* __restrict__ slot,
                 const float* __restrict__ X, short* __restrict__ Xh, short* __restrict__ Xl,
                 const float* __restrict__ W1, const float* __restrict__ W2,
                 short* __restrict__ w1h, short* __restrict__ w1l,
                 short* __restrict__ w2h, short* __restrict__ w2l,
                 const float* __restrict__ b1, const float* __restrict__ b2,
                 float* __restrict__ bs1, float* __restrict__ bs2)
{
    int bid = blockIdx.x, tid = threadIdx.x;
    if (bid < PAIR) {
        if (bid & 1) convx_body(bid >> 1, tid, X, Xh, Xl);
        else         count_body(bid >> 1, tid, src, dst, deg, slot);
    } else {
        int t = bid - PAIR;
        if (t < CB - XB)      count_body(XB + t, tid, src, dst, deg, slot);
        else if ((t -= CB - XB) < WB) convw_body(t, tid, W1, W2, w1h, w1l, w2h, w2l);
        else                  bsum_body(tid, b1, b2, bs1, bs2);
    }
}

// norms for both sides; stash ndst bits into packed rpnd
__global__ __launch_bounds__(256)
void norms_kernel(const unsigned* __restrict__ deg, float* __restrict__ nrm,
                  uint2* __restrict__ rpnd)
{
    int gid = blockIdx.x * 256 + threadIdx.x;
    if (gid >= TOT) return;
    unsigned s = deg[gid], d = deg[TOT + gid];
    nrm[gid] = rsqrtf((float)(s > 0u ? s : 1u));
    rpnd[gid].y = __builtin_bit_cast(unsigned, rsqrtf((float)(d > 0u ? d : 1u)));
}

__global__ __launch_bounds__(256)
void scan1_kernel(const unsigned* __restrict__ deg, unsigned* __restrict__ partial)
{
    __shared__ unsigned s[256];
    int b = blockIdx.x, t = threadIdx.x;
    int start = b * CH;
    int n = TOT - start; if (n > CH) n = CH;
    unsigned sum = 0;
    for (int i = t; i < n; i += 256) sum += deg[TOT + start + i];
    s[t] = sum; __syncthreads();
    for (int d = 128; d > 0; d >>= 1) {
        if (t < d) s[t] += s[t + d];
        __syncthreads();
    }
    if (t == 0) partial[b] = s[0];
}

__global__ __launch_bounds__(1024)
void scan2_kernel(unsigned* __restrict__ partial, unsigned* __restrict__ rowptr)
{
    __shared__ unsigned s[NB1];
    int t = threadIdx.x;
    unsigned orig = partial[t];
    s[t] = orig; __syncthreads();
    for (int d = 1; d < NB1; d <<= 1) {
        unsigned v = (t >= d) ? s[t - d] : 0u;
        __syncthreads();
        s[t] += v;
        __syncthreads();
    }
    partial[t] = s[t] - orig;
    if (t == 0) rowptr[TOT] = (unsigned)RE;
}

__global__ __launch_bounds__(256)
void scan3_kernel(const unsigned* __restrict__ deg, const unsigned* __restrict__ base,
                  unsigned* __restrict__ rowptr, uint2* __restrict__ rpnd)
{
    __shared__ unsigned s[CH];
    int b = blockIdx.x, t = threadIdx.x;
    int start = b * CH;
    int n = TOT - start; if (n > CH) n = CH;
    if (n <= 0) return;
    for (int i = t; i < n; i += 256) s[i] = deg[TOT + start + i];
    __syncthreads();
    if (t == 0) {
        unsigned run = base[b];
        for (int i = 0; i < n; ++i) { unsigned v = s[i]; s[i] = run; run += v; }
    }
    __syncthreads();
    for (int i = t; i < n; i += 256) {
        unsigned v = s[i];
        rowptr[start + i] = v;
        rpnd[start + i].x = v;
    }
}

// ---------------- GEMM body (MFMA, bf16 hi/lo split, bf16 out) ----------------
template<int BN>
__device__ __forceinline__ void gemm_body(
    const short* __restrict__ Xh, const short* __restrict__ Xl,
    const short* __restrict__ WhT_, const short* __restrict__ WlT_,
    short* __restrict__ Y_, int CW, int rowblk, int rel)
{
    constexpr int BM = 128, BKp = 40;            // 32 k + 8 pad
    constexpr int MFR = (BN == 128) ? 4 : 2;
    constexpr int NFR = 4;
    const short* WhT = WhT_ + (size_t)rel * (BN * 128);
    const short* WlT = WlT_ + (size_t)rel * (BN * 128);
    short* Y = Y_ + (size_t)rel * BN;

    __shared__ __align__(16) short Ah[BM * BKp], Al[BM * BKp];
    __shared__ __align__(16) short Bh[BN * BKp], Bl[BN * BKp];

    const int tid = threadIdx.x;
    const int lane = tid & 63, wid = tid >> 6;
    const int lr = lane & 15, lg = lane >> 4;
    const int wm0 = (BN == 128) ? (wid >> 1) * 64 : wid * 32;
    const int wn0 = (BN == 128) ? (wid & 1) * 64 : 0;
    const int row0 = rowblk * BM;

    f32x4 acc[MFR][NFR];
    #pragma unroll
    for (int m = 0; m < MFR; ++m)
        #pragma unroll
        for (int n = 0; n < NFR; ++n)
            #pragma unroll
            for (int j = 0; j < 4; ++j) acc[m][n][j] = 0.f;

    const int sr = tid >> 1;
    const int sko = (tid & 1) * 16;

    for (int ks = 0; ks < 4; ++ks) {
        size_t ga = (size_t)(row0 + sr) * 128 + ks * 32 + sko;
        *reinterpret_cast<bf16x8*>(&Ah[sr * BKp + sko])     = *reinterpret_cast<const bf16x8*>(&Xh[ga]);
        *reinterpret_cast<bf16x8*>(&Ah[sr * BKp + sko + 8]) = *reinterpret_cast<const bf16x8*>(&Xh[ga + 8]);
        *reinterpret_cast<bf16x8*>(&Al[sr * BKp + sko])     = *reinterpret_cast<const bf16x8*>(&Xl[ga]);
        *reinterpret_cast<bf16x8*>(&Al[sr * BKp + sko + 8]) = *reinterpret_cast<const bf16x8*>(&Xl[ga + 8]);
        if (BN == 128 || tid < 128) {
            size_t gb = (size_t)sr * 128 + ks * 32 + sko;
            *reinterpret_cast<bf16x8*>(&Bh[sr * BKp + sko])     = *reinterpret_cast<const bf16x8*>(&WhT[gb]);
            *reinterpret_cast<bf16x8*>(&Bh[sr * BKp + sko + 8]) = *reinterpret_cast<const bf16x8*>(&WhT[gb + 8]);
            *reinterpret_cast<bf16x8*>(&Bl[sr * BKp + sko])     = *reinterpret_cast<const bf16x8*>(&WlT[gb]);
            *reinterpret_cast<bf16x8*>(&Bl[sr * BKp + sko + 8]) = *reinterpret_cast<const bf16x8*>(&WlT[gb + 8]);
        }
        __syncthreads();

        bf16x8 bh[NFR], bl[NFR];
        #pragma unroll
        for (int n = 0; n < NFR; ++n) {
            bh[n] = *reinterpret_cast<const bf16x8*>(&Bh[(wn0 + n * 16 + lr) * BKp + lg * 8]);
            bl[n] = *reinterpret_cast<const bf16x8*>(&Bl[(wn0 + n * 16 + lr) * BKp + lg * 8]);
        }
        #pragma unroll
        for (int m = 0; m < MFR; ++m) {
            bf16x8 ah = *reinterpret_cast<const bf16x8*>(&Ah[(wm0 + m * 16 + lr) * BKp + lg * 8]);
            bf16x8 al = *reinterpret_cast<const bf16x8*>(&Al[(wm0 + m * 16 + lr) * BKp + lg * 8]);
            #pragma unroll
            for (int n = 0; n < NFR; ++n) {
                acc[m][n] = __builtin_amdgcn_mfma_f32_16x16x32_bf16(ah, bh[n], acc[m][n], 0, 0, 0);
                acc[m][n] = __builtin_amdgcn_mfma_f32_16x16x32_bf16(ah, bl[n], acc[m][n], 0, 0, 0);
                acc[m][n] = __builtin_amdgcn_mfma_f32_16x16x32_bf16(al, bh[n], acc[m][n], 0, 0, 0);
            }
        }
        __syncthreads();
    }

    // C/D layout: col=lane&15, row=(lane>>4)*4+j  [m89]
    #pragma unroll
    for (int m = 0; m < MFR; ++m)
        #pragma unroll
        for (int n = 0; n < NFR; ++n) {
            int col = wn0 + n * 16 + lr;
            int rb = row0 + wm0 + m * 16 + lg * 4;
            #pragma unroll
            for (int j = 0; j < 4; ++j)
                Y[(size_t)(rb + j) * CW + col] = (short)f2bf(acc[m][n][j]);
        }
}

// atomic-free CSR fill body: pos = rowptr + slot (4 edges/thread)
__device__ __forceinline__ void fill_body(int sub, int tid,
    const int* __restrict__ src, const int* __restrict__ dst,
    const unsigned* __restrict__ slot, const uint2* __restrict__ rpnd,
    const float* __restrict__ nrm, int2* __restrict__ csrw)
{
    int e0 = (sub * 256 + tid) * 4;
    if (e0 >= RE) return;
    int r = (unsigned)e0 / (unsigned)Ee;
    int base = r * Nn;
    int4 s4 = *reinterpret_cast<const int4*>(src + e0);
    int4 d4 = *reinterpret_cast<const int4*>(dst + e0);
    uint4 sl = *reinterpret_cast<const uint4*>(slot + e0);
    #pragma unroll
    for (int i = 0; i < 4; ++i) {
        int s = (i == 0) ? s4.x : (i == 1) ? s4.y : (i == 2) ? s4.z : s4.w;
        int d = (i == 0) ? d4.x : (i == 1) ? d4.y : (i == 2) ? d4.z : d4.w;
        unsigned k = (i == 0) ? sl.x : (i == 1) ? sl.y : (i == 2) ? sl.z : sl.w;
        uint2 rn = rpnd[base + d];
        float w = nrm[base + s] * __builtin_bit_cast(float, rn.y);
        int2 v; v.x = s; v.y = __builtin_bit_cast(int, w);
        csrw[rn.x + k] = v;
    }
}

// ---------------- fused: fill_csr || gemm128 (all 4 relations) ----------------
__global__ __launch_bounds__(256)
void fill_gemm_kernel(const int* __restrict__ src, const int* __restrict__ dst,
                      const unsigned* __restrict__ slot, const uint2* __restrict__ rpnd,
                      const float* __restrict__ nrm, int2* __restrict__ csrw,
                      const short* __restrict__ Xh, const short* __restrict__ Xl,
                      const short* __restrict__ w1h, const short* __restrict__ w1l,
                      short* __restrict__ Y)
{
    int bid = blockIdx.x, tid = threadIdx.x;
    int role, sub;
    if (bid < PAIR2) { role = bid & 1; sub = bid >> 1; }
    else             { role = 1; sub = FB + (bid - PAIR2); }
    if (role == 0) {
        fill_body(sub, tid, src, dst, slot, rpnd, nrm, csrw);
    } else {
        int rel = sub / NPB, rowblk = sub - rel * NPB;
        gemm_body<128>(Xh, Xl, w1h, w1l, Y, 512, rowblk, rel);
    }
}

// standalone GEMM (layer 2 and path-B): blockIdx.y = relation
template<int BN>
__global__ __launch_bounds__(256)
void gemm_kernel(const short* __restrict__ Xh, const short* __restrict__ Xl,
                 const short* __restrict__ WhT_, const short* __restrict__ WlT_,
                 short* __restrict__ Y_, int CW)
{
    gemm_body<BN>(Xh, Xl, WhT_, WlT_, Y_, CW, blockIdx.x, blockIdx.y);
}

// standalone fill (path B)
__global__ __launch_bounds__(256)
void fill_csr_kernel(const int* __restrict__ src, const int* __restrict__ dst,
                     const unsigned* __restrict__ slot, const uint2* __restrict__ rpnd,
                     const float* __restrict__ nrm, int2* __restrict__ csrw)
{
    fill_body(blockIdx.x, threadIdx.x, src, dst, slot, rpnd, nrm, csrw);
}

// ---------------- CSR gather over NR relations (Y bf16), 4-edge unrolled ----------------
template<int F, int NR>
__global__ __launch_bounds__(256)
void gather_kernel(const short* __restrict__ Y, const unsigned* __restrict__ rowptr,
                   const int2* __restrict__ csrw, const float* __restrict__ bsum,
                   float* __restrict__ H, short* __restrict__ Xh, short* __restrict__ Xl,
                   int CW, int accumulate, int finalize)
{
    constexpr int VF = F / 64;
    int wid = (blockIdx.x * 256 + threadIdx.x) >> 6;
    int lane = threadIdx.x & 63;
    if (wid >= Nn) return;
    float t0 = 0.f, t1 = 0.f;
    #pragma unroll
    for (int rl = 0; rl < NR; ++rl) {
        const short* yr = Y + rl * F;
        unsigned e  = rowptr[rl * Nn + wid];
        unsigned e1 = rowptr[rl * Nn + wid + 1];
        for (; e + 4 <= e1; e += 4) {
            int2 a0 = csrw[e], a1 = csrw[e + 1], a2 = csrw[e + 2], a3 = csrw[e + 3];
            float w0 = __builtin_bit_cast(float, a0.y);
            float w1 = __builtin_bit_cast(float, a1.y);
            float w2 = __builtin_bit_cast(float, a2.y);
            float w3 = __builtin_bit_cast(float, a3.y);
            if constexpr (VF == 2) {
                unsigned p0 = *reinterpret_cast<const unsigned*>(yr + (size_t)a0.x * CW + lane * 2);
                unsigned p1 = *reinterpret_cast<const unsigned*>(yr + (size_t)a1.x * CW + lane * 2);
                unsigned p2 = *reinterpret_cast<const unsigned*>(yr + (size_t)a2.x * CW + lane * 2);
                unsigned p3 = *reinterpret_cast<const unsigned*>(yr + (size_t)a3.x * CW + lane * 2);
                t0 += w0 * bfbits_lo(p0) + w1 * bfbits_lo(p1) + w2 * bfbits_lo(p2) + w3 * bfbits_lo(p3);
                t1 += w0 * bfbits_hi(p0) + w1 * bfbits_hi(p1) + w2 * bfbits_hi(p2) + w3 * bfbits_hi(p3);
            } else {
                unsigned short v0 = *reinterpret_cast<const unsigned short*>(yr + (size_t)a0.x * CW + lane);
                unsigned short v1 = *reinterpret_cast<const unsigned short*>(yr + (size_t)a1.x * CW + lane);
                unsigned short v2 = *reinterpret_cast<const unsigned short*>(yr + (size_t)a2.x * CW + lane);
                unsigned short v3 = *reinterpret_cast<const unsigned short*>(yr + (size_t)a3.x * CW + lane);
                t0 += w0 * bf2f(v0) + w1 * bf2f(v1) + w2 * bf2f(v2) + w3 * bf2f(v3);
            }
        }
        for (; e < e1; ++e) {
            int2 a = csrw[e];
            float wA = __builtin_bit_cast(float, a.y);
            if constexpr (VF == 2) {
                unsigned pA = *reinterpret_cast<const unsigned*>(yr + (size_t)a.x * CW + lane * 2);
                t0 += wA * bfbits_lo(pA);
                t1 += wA * bfbits_hi(pA);
            } else {
                unsigned short vA = *reinterpret_cast<const unsigned short*>(yr + (size_t)a.x * CW + lane);
                t0 += wA * bf2f(vA);
            }
        }
    }
    float* hp = H + (size_t)wid * F + lane * VF;
    if (accumulate) {
        t0 += hp[0]; if (VF == 2) t1 += hp[1];
    } else {
        t0 += bsum[lane * VF]; if (VF == 2) t1 += bsum[lane * VF + 1];
    }
    if (F == 128 && finalize) {
        t0 = fmaxf(t0, 0.f); t1 = fmaxf(t1, 0.f);
        unsigned short h0 = f2bf(t0), h1 = f2bf(t1);
        short2 hv; hv.x = (short)h0; hv.y = (short)h1;
        short2 lv; lv.x = (short)f2bf(t0 - bf2f(h0)); lv.y = (short)f2bf(t1 - bf2f(h1));
        *reinterpret_cast<short2*>(Xh + (size_t)wid * F + lane * 2) = hv;
        *reinterpret_cast<short2*>(Xl + (size_t)wid * F + lane * 2) = lv;
    } else {
        if constexpr (VF == 2) *reinterpret_cast<float2*>(hp) = make_float2(t0, t1);
        else hp[0] = t0;
    }
}

extern "C" void kernel_launch(void* const* d_in, const int* in_sizes, int n_in,
                              void* d_out, int out_size, void* d_ws, size_t ws_size,
                              hipStream_t stream)
{
    const float* x  = (const float*)d_in[0];
    const int* esrc = (const int*)d_in[1];
    const int* edst = (const int*)d_in[2];
    const float* W1 = (const float*)d_in[3];
    const float* b1 = (const float*)d_in[4];
    const float* W2 = (const float*)d_in[5];
    const float* b2 = (const float*)d_in[6];
    float* out = (float*)d_out;

    // ---- workspace layout ----
    char* ws = (char*)d_ws;
    size_t off = 0;
    auto alloc = [&](size_t bytes) { char* p = ws + off; off += (bytes + 255) & ~(size_t)255; return p; };
    unsigned* deg     = (unsigned*)alloc((size_t)2 * TOT * 4);
    float*    nrm     = (float*)   alloc((size_t)TOT * 4);          // nsrc
    uint2*    rpnd    = (uint2*)   alloc((size_t)TOT * 8);          // {rowptr, ndst}
    unsigned* rowptr  = (unsigned*)alloc((size_t)(TOT + 1) * 4);
    unsigned* partial = (unsigned*)alloc((size_t)NB1 * 4);
    unsigned* slot    = (unsigned*)alloc((size_t)RE * 4);
    float*    bs1     = (float*)   alloc(128 * 4);
    float*    bs2     = (float*)   alloc(64 * 4);
    short*    w1h     = (short*)   alloc((size_t)4 * 128 * 128 * 2);
    short*    w1l     = (short*)   alloc((size_t)4 * 128 * 128 * 2);
    short*    w2h     = (short*)   alloc((size_t)4 * 64 * 128 * 2);
    short*    w2l     = (short*)   alloc((size_t)4 * 64 * 128 * 2);
    int2*     csrw    = (int2*)    alloc((size_t)RE * 8);
    short*    xh      = (short*)   alloc((size_t)NP * 128 * 2);
    short*    xl      = (short*)   alloc((size_t)NP * 128 * 2);

    size_t yslot = (size_t)NP * 128 * 2;          // 25.6MB (bf16, 128 cols)
    bool pathA = (ws_size >= off + 4 * yslot + 4096);
    float* h = nullptr;
    short* Y;
    if (pathA) {
        Y = (short*)alloc(4 * yslot);
    } else {
        h = (float*)alloc((size_t)NP * 128 * 4);
        Y = (short*)alloc(yslot);
    }

    // ---- phase 1: fused prep (count || convx || convw || bsum) ----
    hipMemsetAsync(deg, 0, (size_t)2 * TOT * 4, stream);
    prep_kernel<<<PREP_GRID, 256, 0, stream>>>(
        esrc, edst, deg, slot, x, xh, xl, W1, W2,
        w1h, w1l, w2h, w2l, b1, b2, bs1, bs2);

    // ---- phase 2: norms + scan ----
    norms_kernel<<<(TOT + 255) / 256, 256, 0, stream>>>(deg, nrm, rpnd);
    scan1_kernel<<<NB1, 256, 0, stream>>>(deg, partial);
    scan2_kernel<<<1, NB1, 0, stream>>>(partial, rowptr);
    scan3_kernel<<<NB1, 256, 0, stream>>>(deg, partial, rowptr, rpnd);

    const int ggrid = (Nn * 64 + 255) / 256;      // one wave per dst node

    if (pathA) {
        // ---- phase 3: fill_csr || gemm128 (4 rel) fused ----
        fill_gemm_kernel<<<FG_GRID, 256, 0, stream>>>(
            esrc, edst, slot, rpnd, nrm, csrw, xh, xl, w1h, w1l, Y);
        // ---- phase 4: layer-1 gather (finalize: bias+ReLU+split into xh/xl) ----
        gather_kernel<128, 4><<<ggrid, 256, 0, stream>>>(
            Y, rowptr, csrw, bs1, out /*unused*/, xh, xl, 512, 0, 1);
        // ---- phase 5: layer-2 GEMM + gather ----
        gemm_kernel<64><<<dim3(NPB, 4), 256, 0, stream>>>(xh, xl, w2h, w2l, Y, 256);
        gather_kernel<64, 4><<<ggrid, 256, 0, stream>>>(
            Y, rowptr, csrw, bs2, out, nullptr, nullptr, 256, 0, 0);
    } else {
        fill_csr_kernel<<<FB, 256, 0, stream>>>(esrc, edst, slot, rpnd, nrm, csrw);
        for (int r = 0; r < Rr; ++r) {
            gemm_kernel<128><<<dim3(NPB, 1), 256, 0, stream>>>(
                xh, xl, w1h + (size_t)r * 128 * 128, w1l + (size_t)r * 128 * 128, Y, 128);
            gather_kernel<128, 1><<<ggrid, 256, 0, stream>>>(
                Y, rowptr + (size_t)r * Nn, csrw, bs1, h, xh, xl, 128, r > 0, r == Rr - 1);
        }
        for (int r = 0; r < Rr; ++r) {
            gemm_kernel<64><<<dim3(NPB, 1), 256, 0, stream>>>(
                xh, xl, w2h + (size_t)r * 64 * 128, w2l + (size_t)r * 64 * 128, Y, 64);
            gather_kernel<64, 1><<<ggrid, 256, 0, stream>>>(
                Y, rowptr + (size_t)r * Nn, csrw, bs2, out, nullptr, nullptr, 64, r > 0, 0);
        }
    }
}